// Round 2
// baseline (2073.729 us; speedup 1.0000x reference)
//
#include <hip/hip_runtime.h>

// Qwen3.5 GatedDeltaNet fwd on gfx950.
// B=2 T=2048 HID=2048 HK=16 HV=32 DK=DV=128 KW=4
// bf16 intermediates; workspace footprint 169,345,024 B with lifetime overlays.

#define T_LEN 2048
#define MROWS 4096   // B*T
#define ZBA_LD 4224  // 4096 z + 32 beta + 32 alpha + 64 pad

typedef __bf16 bf16x8 __attribute__((ext_vector_type(8)));
typedef float f32x4 __attribute__((ext_vector_type(4)));

__device__ __forceinline__ unsigned short f2bf(float f) {
  unsigned int u = __float_as_uint(f);
  unsigned int r = (u + 0x7fffu + ((u >> 16) & 1u)) >> 16;
  return (unsigned short)r;
}
__device__ __forceinline__ float bf2f(unsigned short u) {
  return __uint_as_float(((unsigned int)u) << 16);
}

__device__ __forceinline__ void gload_lds16(const void* g, void* l) {
  __builtin_amdgcn_global_load_lds(
      (const __attribute__((address_space(1))) unsigned int*)g,
      (__attribute__((address_space(3))) unsigned int*)l, 16, 0, 0);
}

// ---------------- elementwise f32 -> bf16 ----------------
__global__ __launch_bounds__(256) void f32_to_bf16_vec(const float* __restrict__ src,
                                                       unsigned short* __restrict__ dst,
                                                       int n4) {
  int i = blockIdx.x * 256 + threadIdx.x;
  if (i >= n4) return;
  float4 v = ((const float4*)src)[i];
  ushort4 o;
  o.x = f2bf(v.x); o.y = f2bf(v.y); o.z = f2bf(v.z); o.w = f2bf(v.w);
  ((ushort4*)dst)[i] = o;
}

// ---------------- transpose f32 [R,C] -> bf16 [C,R] ----------------
__global__ __launch_bounds__(256) void transpose_f2b(const float* __restrict__ src,
                                                     unsigned short* __restrict__ dst,
                                                     int R, int C) {
  __shared__ float tile[32][33];
  int tx = threadIdx.x & 31, ty = threadIdx.x >> 5;
  int c0 = blockIdx.x * 32, r0 = blockIdx.y * 32;
  #pragma unroll
  for (int i = ty; i < 32; i += 8)
    tile[i][tx] = src[(size_t)(r0 + i) * C + c0 + tx];
  __syncthreads();
  #pragma unroll
  for (int i = ty; i < 32; i += 8)
    dst[(size_t)(c0 + i) * R + r0 + tx] = f2bf(tile[tx][i]);
}

// ---------------- bf16 MFMA GEMM: C[M,N] = A[M,K] @ Bt[N,K]^T ----------------
// 128x128 tile, BK=64, 4 waves (2x2), 4x4 16x16x32 frags/wave, global_load_lds.
template <int OUTBF>
__global__ __launch_bounds__(256) void gemm_bf16(const unsigned short* __restrict__ A,
                                                 const unsigned short* __restrict__ Bt,
                                                 void* __restrict__ Cv,
                                                 int M, int N, int K) {
  __shared__ unsigned short As[128 * 64];
  __shared__ unsigned short Bs[128 * 64];
  const int tid = threadIdx.x, lane = tid & 63, wv = tid >> 6;
  const int wr = wv >> 1, wc = wv & 1;
  const int m0 = blockIdx.y * 128, n0 = blockIdx.x * 128;
  const int lrow8 = lane >> 3;
  const int lk8 = (lane & 7) * 8;

  f32x4 acc[4][4];
  #pragma unroll
  for (int i = 0; i < 4; i++)
    #pragma unroll
    for (int j = 0; j < 4; j++) acc[i][j] = f32x4{0.f, 0.f, 0.f, 0.f};

  for (int k0 = 0; k0 < K; k0 += 64) {
    #pragma unroll
    for (int j = 0; j < 4; ++j) {
      int chunk = j * 4 + wv;
      int r = chunk * 8 + lrow8;
      gload_lds16(A + (size_t)(m0 + r) * K + k0 + lk8, (void*)(As + chunk * 512));
      gload_lds16(Bt + (size_t)(n0 + r) * K + k0 + lk8, (void*)(Bs + chunk * 512));
    }
    __syncthreads();
    #pragma unroll
    for (int half = 0; half < 2; ++half) {
      int ko = half * 32 + (lane >> 4) * 8;
      bf16x8 af[4], bfr[4];
      #pragma unroll
      for (int i = 0; i < 4; i++) {
        int ra = wr * 64 + i * 16 + (lane & 15);
        af[i] = *(const bf16x8*)(As + ra * 64 + ko);
        int rb = wc * 64 + i * 16 + (lane & 15);
        bfr[i] = *(const bf16x8*)(Bs + rb * 64 + ko);
      }
      #pragma unroll
      for (int i = 0; i < 4; i++)
        #pragma unroll
        for (int j = 0; j < 4; j++)
          acc[i][j] = __builtin_amdgcn_mfma_f32_16x16x32_bf16(af[i], bfr[j], acc[i][j], 0, 0, 0);
    }
    __syncthreads();
  }
  int cr4 = (lane >> 4) * 4;
  int cc = lane & 15;
  #pragma unroll
  for (int i = 0; i < 4; i++) {
    int row = m0 + wr * 64 + i * 16 + cr4;
    #pragma unroll
    for (int j = 0; j < 4; j++) {
      int col = n0 + wc * 64 + j * 16 + cc;
      if (OUTBF) {
        unsigned short* cp = (unsigned short*)Cv + (size_t)row * N + col;
        #pragma unroll
        for (int r = 0; r < 4; r++) cp[(size_t)r * N] = f2bf(acc[i][j][r]);
      } else {
        float* cp = (float*)Cv + (size_t)row * N + col;
        #pragma unroll
        for (int r = 0; r < 4; r++) cp[(size_t)r * N] = acc[i][j][r];
      }
    }
  }
}

// ---------------- beta / gexp from z_ba cols [4096..4160) (bf16 in) ----------------
__global__ __launch_bounds__(256) void beta_g_kernel(const unsigned short* __restrict__ z_ba,
                                                     const float* __restrict__ A_log,
                                                     const float* __restrict__ dt_bias,
                                                     float* __restrict__ beta,
                                                     float* __restrict__ gexp) {
  int i = blockIdx.x * 256 + threadIdx.x;  // row*32 + hv, rows = 4096
  int row = i >> 5, hv = i & 31;
  float rb = bf2f(z_ba[(size_t)row * ZBA_LD + 4096 + hv]);
  float ra = bf2f(z_ba[(size_t)row * ZBA_LD + 4128 + hv]);
  beta[i] = 1.f / (1.f + expf(-rb));
  float xg = ra + dt_bias[hv];
  float sp = (xg > 20.f) ? xg : log1pf(expf(xg));
  gexp[i] = expf(-expf(A_log[hv]) * sp);
}

// ---- fused scan: conv4+SiLU+l2norm on staged tiles, then gated delta recurrence ----
// grid (8 dv-slices, 64 bh); block 256.
__global__ __launch_bounds__(256) void scan_kernel(const unsigned short* __restrict__ qkv,
                                                   const float* __restrict__ beta,
                                                   const float* __restrict__ gexp,
                                                   const float* __restrict__ conv_w,
                                                   unsigned short* __restrict__ o, int T) {
  const int bh = blockIdx.y;
  const int b = bh >> 5, hv = bh & 31, hk = hv >> 1;
  const int dv0 = blockIdx.x * 16;
  const int t = threadIdx.x;

  // raw qkv columns
  const int cq = hk * 512;
  const int ck = hk * 512 + 128;
  const int cv = hk * 512 + 256 + (hv & 1) * 128 + dv0;
  // mixed-channel conv-weight rows
  const int wq0 = hk * 128;
  const int wk0 = 2048 + hk * 128;
  const int wv0 = 4096 + hv * 128 + dv0;

  __shared__ unsigned short rawq[35][136], rawk[35][136], rawv[35][16];
  __shared__ float qn[32][132], kn[32][132], vt[32][16];
  __shared__ float o_s[32][16];
  __shared__ float eg_s[32], bt_s[32], sq_s[32], sk_s[32];
  __shared__ float cwt[4][272];  // taps x (q 0..127 | k 128..255 | v 256..271)

  // conv-weight staging (once)
  for (int i = t; i < 1088; i += 256) {
    int row = i >> 2, tap = i & 3;
    int src = (row < 128) ? (wq0 + row) : (row < 256) ? (wk0 + row - 128) : (wv0 + row - 256);
    cwt[tap][row] = conv_w[(size_t)src * 4 + tap];
  }

  float S[8];
  #pragma unroll
  for (int i = 0; i < 8; i++) S[i] = 0.f;

  const size_t rowbase = (size_t)(b * T) * 8192;
  const size_t orow = (size_t)(b * T) * 4096;
  const float* egp = gexp + (size_t)(b * T) * 32 + hv;
  const float* btp = beta + (size_t)(b * T) * 32 + hv;

  const int s = t >> 3, dg = t & 7;          // conv mapping: row, 16-ch group
  const int dvl = t >> 4, dk0 = (t & 15) * 8; // scan mapping

  for (int s0 = 0; s0 < T; s0 += 32) {
    // ---- stage raw rows s0-3 .. s0+31 (35 rows) of q(128) k(128) v(16) ----
    for (int i = t; i < 1190; i += 256) {
      unsigned short* dst;
      int gcol, row;
      if (i < 1120) {
        row = i >> 5;
        int part = i & 31;
        if (part < 16) { dst = &rawq[row][part * 8]; gcol = cq + part * 8; }
        else           { dst = &rawk[row][(part - 16) * 8]; gcol = ck + (part - 16) * 8; }
      } else {
        int j = i - 1120;
        row = j >> 1;
        dst = &rawv[row][(j & 1) * 8];
        gcol = cv + (j & 1) * 8;
      }
      int gt = s0 - 3 + row;
      uint4 val = make_uint4(0u, 0u, 0u, 0u);
      if (gt >= 0) val = *(const uint4*)(qkv + rowbase + (size_t)gt * 8192 + gcol);
      *(uint4*)dst = val;
    }
    if (t < 32) eg_s[t] = egp[(size_t)(s0 + t) * 32];
    else if (t < 64) bt_s[t - 32] = btp[(size_t)(s0 + t - 32) * 32];
    __syncthreads();

    // ---- conv4 + SiLU + row sums (thread: row s, channels dg*16..+16) ----
    union RawU { uint4 v[2]; unsigned short h[16]; };
    RawU uq[4], uk[4];
    #pragma unroll
    for (int i = 0; i < 4; i++) {
      const uint4* pq = (const uint4*)&rawq[s + i][dg * 16];
      uq[i].v[0] = pq[0]; uq[i].v[1] = pq[1];
      const uint4* pk = (const uint4*)&rawk[s + i][dg * 16];
      uk[i].v[0] = pk[0]; uk[i].v[1] = pk[1];
    }
    float ssq = 0.f, ssk = 0.f;
    #pragma unroll
    for (int j4 = 0; j4 < 4; j4++) {
      float aqv[4], akv[4];
      #pragma unroll
      for (int jj = 0; jj < 4; jj++) {
        int j = j4 * 4 + jj;
        int d = dg * 16 + j;
        float aq = 0.f, ak = 0.f;
        #pragma unroll
        for (int i = 0; i < 4; i++) {
          aq = fmaf(cwt[i][d], bf2f(uq[i].h[j]), aq);
          ak = fmaf(cwt[i][128 + d], bf2f(uk[i].h[j]), ak);
        }
        aq = aq / (1.f + expf(-aq));
        ak = ak / (1.f + expf(-ak));
        aqv[jj] = aq; akv[jj] = ak;
        ssq += aq * aq; ssk += ak * ak;
      }
      *(float4*)&qn[s][dg * 16 + j4 * 4] = make_float4(aqv[0], aqv[1], aqv[2], aqv[3]);
      *(float4*)&kn[s][dg * 16 + j4 * 4] = make_float4(akv[0], akv[1], akv[2], akv[3]);
    }
    // v: 2 channels per thread
    #pragma unroll
    for (int j = 0; j < 2; j++) {
      int d = dg * 2 + j;
      float av = 0.f;
      #pragma unroll
      for (int i = 0; i < 4; i++) av = fmaf(cwt[i][256 + d], bf2f(rawv[s + i][d]), av);
      vt[s][d] = av / (1.f + expf(-av));
    }
    // row l2 scales (8 lanes per row, consecutive within a wave)
    ssq += __shfl_xor(ssq, 1); ssq += __shfl_xor(ssq, 2); ssq += __shfl_xor(ssq, 4);
    ssk += __shfl_xor(ssk, 1); ssk += __shfl_xor(ssk, 2); ssk += __shfl_xor(ssk, 4);
    if (dg == 0) {
      sq_s[s] = rsqrtf(ssq + 1e-6f) * 0.08838834764831845f;  // * DK^-0.5
      sk_s[s] = rsqrtf(ssk + 1e-6f);
    }
    __syncthreads();

    // ---- 32 recurrence steps ----
    #pragma unroll 2
    for (int st = 0; st < 32; st++) {
      float eg = eg_s[st], bt = bt_s[st];
      float skk = sk_s[st], sqq = sq_s[st];
      const float4* kp = (const float4*)&kn[st][dk0];
      float4 k1 = kp[0], k2 = kp[1];
      k1.x *= skk; k1.y *= skk; k1.z *= skk; k1.w *= skk;
      k2.x *= skk; k2.y *= skk; k2.z *= skk; k2.w *= skk;
      float p0 = k1.x * S[0] + k1.y * S[1] + k2.x * S[4] + k2.y * S[5];
      float p1 = k1.z * S[2] + k1.w * S[3] + k2.z * S[6] + k2.w * S[7];
      float p = p0 + p1;
      p += __shfl_xor(p, 1);
      p += __shfl_xor(p, 2);
      p += __shfl_xor(p, 4);
      p += __shfl_xor(p, 8);
      float delta = bt * (vt[st][dvl] - eg * p);
      S[0] = eg * S[0] + k1.x * delta; S[1] = eg * S[1] + k1.y * delta;
      S[2] = eg * S[2] + k1.z * delta; S[3] = eg * S[3] + k1.w * delta;
      S[4] = eg * S[4] + k2.x * delta; S[5] = eg * S[5] + k2.y * delta;
      S[6] = eg * S[6] + k2.z * delta; S[7] = eg * S[7] + k2.w * delta;
      const float4* qp = (const float4*)&qn[st][dk0];
      float4 q1 = qp[0], q2 = qp[1];
      float r0 = (q1.x * S[0] + q1.y * S[1] + q2.x * S[4] + q2.y * S[5]) * sqq;
      float r1 = (q1.z * S[2] + q1.w * S[3] + q2.z * S[6] + q2.w * S[7]) * sqq;
      float r = r0 + r1;
      r += __shfl_xor(r, 1);
      r += __shfl_xor(r, 2);
      r += __shfl_xor(r, 4);
      r += __shfl_xor(r, 8);
      if ((t & 15) == 0) o_s[st][dvl] = r;
    }
    __syncthreads();
    if (t < 128) {
      int sr = t >> 2, c4 = (t & 3) * 4;
      const float* osp = &o_s[sr][c4];
      ushort4 ov;
      ov.x = f2bf(osp[0]); ov.y = f2bf(osp[1]); ov.z = f2bf(osp[2]); ov.w = f2bf(osp[3]);
      *(ushort4*)(o + orow + (size_t)(s0 + sr) * 4096 + hv * 128 + dv0 + c4) = ov;
    }
  }
}

// ---------------- gated RMSNorm in-place on o (bf16) ----------------
__global__ __launch_bounds__(256) void rmsgate_kernel(unsigned short* __restrict__ o,
                                                      const unsigned short* __restrict__ z_ba,
                                                      const float* __restrict__ nw) {
  int wid = blockIdx.x * 4 + (threadIdx.x >> 6);
  int lane = threadIdx.x & 63;
  int row = wid >> 5;
  int hv = wid & 31;
  unsigned short* op = o + (size_t)row * 4096 + hv * 128;
  float o0 = bf2f(op[lane]), o1 = bf2f(op[64 + lane]);
  float ss = o0 * o0 + o1 * o1;
  #pragma unroll
  for (int m = 1; m < 64; m <<= 1) ss += __shfl_xor(ss, m);
  float r = rsqrtf(ss * (1.f / 128.f) + 1e-6f);
  const unsigned short* zp = z_ba + (size_t)row * ZBA_LD + hv * 128;
  float g0 = bf2f(zp[lane]), g1 = bf2f(zp[64 + lane]);
  g0 = g0 / (1.f + expf(-g0));
  g1 = g1 / (1.f + expf(-g1));
  op[lane] = f2bf(o0 * r * g0 * nw[lane]);
  op[64 + lane] = f2bf(o1 * r * g1 * nw[64 + lane]);
}

extern "C" void kernel_launch(void* const* d_in, const int* in_sizes, int n_in,
                              void* d_out, int out_size, void* d_ws, size_t ws_size,
                              hipStream_t stream) {
  (void)in_sizes; (void)n_in; (void)out_size;
  const float* x       = (const float*)d_in[0];
  const float* W_qkv   = (const float*)d_in[1];
  const float* W_z     = (const float*)d_in[2];
  const float* W_b     = (const float*)d_in[3];
  const float* W_a     = (const float*)d_in[4];
  const float* conv_w  = (const float*)d_in[5];
  const float* dt_bias = (const float*)d_in[6];
  const float* A_log   = (const float*)d_in[7];
  const float* nw      = (const float*)d_in[8];
  const float* W_out   = (const float*)d_in[9];
  float* out = (float*)d_out;

  // workspace layout with lifetime overlays; total 169,345,024 B
  const size_t NEED = 169345024ULL;
  if (ws_size < NEED) return;  // clean diagnostic fail instead of OOB crash

  char* ws = (char*)d_ws;
  unsigned short* qkv_bf = (unsigned short*)(ws + 0);          // [4096][8192] bf16
  unsigned short* z_ba   = (unsigned short*)(ws + 67108864);   // [4096][4224] bf16
  unsigned short* WqkvT  = (unsigned short*)(ws + 101711872);  // [8192][2048] bf16
  unsigned short* o_bf   = (unsigned short*)(ws + 101711872);  // overlay (after GEMM1)
  unsigned short* x_bf   = (unsigned short*)(ws + 135266304);  // [4096][2048] bf16
  unsigned short* WoutT  = (unsigned short*)(ws + 135266304);  // overlay (after GEMM2)
  unsigned short* WzbaT  = (unsigned short*)(ws + 152043520);  // [4224][2048] bf16
  float* beta            = (float*)(ws + 152043520);           // overlay (after GEMM2)
  float* gexp            = (float*)(ws + 152567808);

  const int T = T_LEN, M = MROWS;

  // 1) conversions + weight transposes
  f32_to_bf16_vec<<<(M * 2048 / 4) / 256, 256, 0, stream>>>(x, x_bf, M * 2048 / 4);
  transpose_f2b<<<dim3(8192 / 32, 2048 / 32), 256, 0, stream>>>(W_qkv, WqkvT, 2048, 8192);
  transpose_f2b<<<dim3(4096 / 32, 2048 / 32), 256, 0, stream>>>(W_z, WzbaT, 2048, 4096);
  transpose_f2b<<<dim3(1, 64), 256, 0, stream>>>(W_b, WzbaT + (size_t)4096 * 2048, 2048, 32);
  transpose_f2b<<<dim3(1, 64), 256, 0, stream>>>(W_a, WzbaT + (size_t)4128 * 2048, 2048, 32);

  // 2) projections (bf16 out)
  gemm_bf16<1><<<dim3(8192 / 128, M / 128), 256, 0, stream>>>(x_bf, WqkvT, qkv_bf, M, 8192, 2048);
  gemm_bf16<1><<<dim3(ZBA_LD / 128, M / 128), 256, 0, stream>>>(x_bf, WzbaT, z_ba, M, ZBA_LD, 2048);

  // 3) W_out transpose (overlays x_bf, dead after GEMM2)
  transpose_f2b<<<dim3(2048 / 32, 4096 / 32), 256, 0, stream>>>(W_out, WoutT, 4096, 2048);

  // 4) gates (overlay WzbaT, dead after GEMM2)
  beta_g_kernel<<<(M * 32) / 256, 256, 0, stream>>>(z_ba, A_log, dt_bias, beta, gexp);

  // 5) fused conv + recurrence -> o (overlays WqkvT, dead after GEMM1)
  scan_kernel<<<dim3(8, 64), 256, 0, stream>>>(qkv_bf, beta, gexp, conv_w, o_bf, T);

  // 6) gated RMSNorm in place, then final GEMM -> f32 out
  rmsgate_kernel<<<32768, 256, 0, stream>>>(o_bf, z_ba, nw);
  gemm_bf16<0><<<dim3(2048 / 128, M / 128), 256, 0, stream>>>(o_bf, WoutT, out, M, 2048, 4096);
}

// Round 3
// 838.129 us; speedup vs baseline: 2.4742x; 2.4742x over previous
//
#include <hip/hip_runtime.h>

// Qwen3.5 GatedDeltaNet fwd on gfx950 — chunked delta-rule version.
// B=2 T=2048 HID=2048 HK=16 HV=32 DK=DV=128 KW=4, chunk C=64 (32 chunks).

#define T_LEN 2048
#define MROWS 4096
#define CPAD 65

typedef __bf16 bf16x8 __attribute__((ext_vector_type(8)));
typedef float f32x4 __attribute__((ext_vector_type(4)));

#define MFMA(a, b, c) __builtin_amdgcn_mfma_f32_16x16x32_bf16((a), (b), (c), 0, 0, 0)

__device__ __forceinline__ unsigned short f2bf(float f) {
  unsigned int u = __float_as_uint(f);
  unsigned int r = (u + 0x7fffu + ((u >> 16) & 1u)) >> 16;
  return (unsigned short)r;
}
__device__ __forceinline__ float bf2f(unsigned short u) {
  return __uint_as_float(((unsigned int)u) << 16);
}
__device__ __forceinline__ void gload_lds16(const void* g, void* l) {
  __builtin_amdgcn_global_load_lds(
      (const __attribute__((address_space(1))) unsigned int*)g,
      (__attribute__((address_space(3))) unsigned int*)l, 16, 0, 0);
}

// ---------------- elementwise f32 -> bf16 ----------------
__global__ __launch_bounds__(256) void f32_to_bf16_vec(const float* __restrict__ src,
                                                       unsigned short* __restrict__ dst,
                                                       int n4) {
  int i = blockIdx.x * 256 + threadIdx.x;
  if (i >= n4) return;
  float4 v = ((const float4*)src)[i];
  ushort4 o;
  o.x = f2bf(v.x); o.y = f2bf(v.y); o.z = f2bf(v.z); o.w = f2bf(v.w);
  ((ushort4*)dst)[i] = o;
}

// ---------------- transpose f32 [R,C] -> bf16 [C,R] ----------------
__global__ __launch_bounds__(256) void transpose_f2b(const float* __restrict__ src,
                                                     unsigned short* __restrict__ dst,
                                                     int R, int C) {
  __shared__ float tile[32][33];
  int tx = threadIdx.x & 31, ty = threadIdx.x >> 5;
  int c0 = blockIdx.x * 32, r0 = blockIdx.y * 32;
  #pragma unroll
  for (int i = ty; i < 32; i += 8)
    tile[i][tx] = src[(size_t)(r0 + i) * C + c0 + tx];
  __syncthreads();
  #pragma unroll
  for (int i = ty; i < 32; i += 8)
    dst[(size_t)(c0 + i) * R + r0 + tx] = f2bf(tile[tx][i]);
}

// ------- bf16 MFMA GEMM: C[M,N] = A[M,K](lda) @ Bt[N,K](ldb)^T, out ldc -------
template <int OUTBF>
__global__ __launch_bounds__(256) void gemm_bf16(const unsigned short* __restrict__ A, int lda,
                                                 const unsigned short* __restrict__ Bt, int ldb,
                                                 void* __restrict__ Cv, int ldc,
                                                 int M, int N, int K) {
  __shared__ unsigned short As[128 * 64];
  __shared__ unsigned short Bs[128 * 64];
  const int tid = threadIdx.x, lane = tid & 63, wv = tid >> 6;
  const int wr = wv >> 1, wc = wv & 1;
  const int m0 = blockIdx.y * 128, n0 = blockIdx.x * 128;
  const int lrow8 = lane >> 3;
  const int lk8 = (lane & 7) * 8;

  f32x4 acc[4][4];
  #pragma unroll
  for (int i = 0; i < 4; i++)
    #pragma unroll
    for (int j = 0; j < 4; j++) acc[i][j] = f32x4{0.f, 0.f, 0.f, 0.f};

  for (int k0 = 0; k0 < K; k0 += 64) {
    #pragma unroll
    for (int j = 0; j < 4; ++j) {
      int chunk = j * 4 + wv;
      int r = chunk * 8 + lrow8;
      gload_lds16(A + (size_t)(m0 + r) * lda + k0 + lk8, (void*)(As + chunk * 512));
      gload_lds16(Bt + (size_t)(n0 + r) * ldb + k0 + lk8, (void*)(Bs + chunk * 512));
    }
    __syncthreads();
    #pragma unroll
    for (int half = 0; half < 2; ++half) {
      int ko = half * 32 + (lane >> 4) * 8;
      bf16x8 af[4], bfr[4];
      #pragma unroll
      for (int i = 0; i < 4; i++) {
        int ra = wr * 64 + i * 16 + (lane & 15);
        af[i] = *(const bf16x8*)(As + ra * 64 + ko);
        int rb = wc * 64 + i * 16 + (lane & 15);
        bfr[i] = *(const bf16x8*)(Bs + rb * 64 + ko);
      }
      #pragma unroll
      for (int i = 0; i < 4; i++)
        #pragma unroll
        for (int j = 0; j < 4; j++)
          acc[i][j] = MFMA(af[i], bfr[j], acc[i][j]);
    }
    __syncthreads();
  }
  int cr4 = (lane >> 4) * 4;
  int cc = lane & 15;
  #pragma unroll
  for (int i = 0; i < 4; i++) {
    int row = m0 + wr * 64 + i * 16 + cr4;
    #pragma unroll
    for (int j = 0; j < 4; j++) {
      int col = n0 + wc * 64 + j * 16 + cc;
      if (OUTBF) {
        unsigned short* cp = (unsigned short*)Cv + (size_t)row * ldc + col;
        #pragma unroll
        for (int r = 0; r < 4; r++) cp[(size_t)r * ldc] = f2bf(acc[i][j][r]);
      } else {
        float* cp = (float*)Cv + (size_t)row * ldc + col;
        #pragma unroll
        for (int r = 0; r < 4; r++) cp[(size_t)r * ldc] = acc[i][j][r];
      }
    }
  }
}

// ---------------- beta / g from ba (bf16 [4096][128]: cols 0-31 b, 32-63 a) ----------------
__global__ __launch_bounds__(256) void beta_g_kernel(const unsigned short* __restrict__ ba,
                                                     const float* __restrict__ A_log,
                                                     const float* __restrict__ dt_bias,
                                                     unsigned short* __restrict__ betab,
                                                     float* __restrict__ g) {
  int i = blockIdx.x * 256 + threadIdx.x;  // row*32+hv, rows=4096
  int row = i >> 5, hv = i & 31;
  float rb = bf2f(ba[(size_t)row * 128 + hv]);
  float ra = bf2f(ba[(size_t)row * 128 + 32 + hv]);
  betab[i] = f2bf(1.f / (1.f + expf(-rb)));
  float xg = ra + dt_bias[hv];
  float sp = (xg > 20.f) ? xg : log1pf(expf(xg));
  g[i] = -expf(A_log[hv]) * sp;
}

// ------- conv4 + SiLU + q/k l2norm (permutes to mixed layout), bf16 in/out -------
// grid (64 segs, 64 t-tiles, 2 b); block 256
__global__ __launch_bounds__(256) void conv_kernel(const unsigned short* __restrict__ qkv,
                                                   const float* __restrict__ conv_w,
                                                   unsigned short* __restrict__ out) {
  const int seg = blockIdx.x, tt = blockIdx.y, b = blockIdx.z;
  const int tid = threadIdx.x;
  const int c0 = seg * 128;
  const bool isq = seg < 16;
  int scb;
  if (isq) scb = seg * 512;
  else if (seg < 32) scb = (seg - 16) * 512 + 128;
  else scb = ((seg - 32) >> 1) * 512 + 256 + ((seg - 32) & 1) * 128;

  __shared__ unsigned short raw[35][136];
  __shared__ float cw[4][132];

  for (int i = tid; i < 512; i += 256) {
    int cl = i >> 2, tap = i & 3;
    cw[tap][cl] = conv_w[(size_t)(c0 + cl) * 4 + tap];
  }
  const int t0 = tt * 32;
  for (int i = tid; i < 560; i += 256) {   // 35 rows x 16 uint4
    int row = i >> 4, col = (i & 15) * 8;
    int gt = t0 - 3 + row;
    uint4 v = make_uint4(0u, 0u, 0u, 0u);
    if (gt >= 0) v = *(const uint4*)(qkv + (size_t)(b * T_LEN + gt) * 8192 + scb + col);
    *(uint4*)(&raw[row][col]) = v;
  }
  __syncthreads();
  const int s = tid >> 3, dg = tid & 7;
  union RawU { uint4 v[2]; unsigned short h[16]; };
  RawU u[4];
  #pragma unroll
  for (int i = 0; i < 4; i++) {
    const uint4* p = (const uint4*)&raw[s + i][dg * 16];
    u[i].v[0] = p[0]; u[i].v[1] = p[1];
  }
  float vals[16]; float ss = 0.f;
  #pragma unroll
  for (int j = 0; j < 16; j++) {
    float a = 0.f;
    #pragma unroll
    for (int i = 0; i < 4; i++) a = fmaf(cw[i][dg * 16 + j], bf2f(u[i].h[j]), a);
    a = a / (1.f + expf(-a));
    vals[j] = a; ss += a * a;
  }
  if (seg < 32) {
    ss += __shfl_xor(ss, 1); ss += __shfl_xor(ss, 2); ss += __shfl_xor(ss, 4);
    float sc = rsqrtf(ss + 1e-6f);
    if (isq) sc *= 0.08838834764831845f;  // DK^-0.5
    #pragma unroll
    for (int j = 0; j < 16; j++) vals[j] *= sc;
  }
  union { uint4 v[2]; unsigned short h[16]; } ov;
  #pragma unroll
  for (int j = 0; j < 16; j++) ov.h[j] = f2bf(vals[j]);
  unsigned short* op = out + (size_t)(b * T_LEN + t0 + s) * 8192 + c0 + dg * 16;
  *(uint4*)(op) = ov.v[0];
  *(uint4*)(op + 8) = ov.v[1];
}

// ---------------- prep: per chunk-head precompute M1, M2, vecs ----------------
// grid (32 chunks, 64 bh); block 256 (4 waves)
__global__ __launch_bounds__(256) void prep_kernel(const unsigned short* __restrict__ conv,
                                                   const float* __restrict__ g,
                                                   const unsigned short* __restrict__ betab,
                                                   unsigned short* __restrict__ M1g,
                                                   unsigned short* __restrict__ M2g,
                                                   unsigned char* __restrict__ vecs) {
  const int c = blockIdx.x, bh = blockIdx.y;
  const int b = bh >> 5, hv = bh & 31, hk = hv >> 1;
  const int bhc = bh * 32 + c;
  const int tid = threadIdx.x, lane = tid & 63, wv = tid >> 6;
  const int r0 = b * T_LEN + c * 64;

  __shared__ unsigned short Kb[128 * 72];   // K [64][136] then KT [128][72]
  __shared__ unsigned short Qb[64 * 136];   // Q then XT f32 [64][65]
  __shared__ float Ab[64 * CPAD];           // A f32, later XTb bf16 [64][72]
  __shared__ unsigned short Pb[64 * 72];
  __shared__ float Gs[64], Ls[64], SCs[64], BLs[64];

  // step 0: decay prefix + vecs (wave 0)
  if (wv == 0) {
    float gt = g[(size_t)(r0 + lane) * 32 + hv];
    #pragma unroll
    for (int d = 1; d < 64; d <<= 1) {
      float o = __shfl_up(gt, (unsigned)d, 64);
      if (lane >= d) gt += o;
    }
    float GC = __shfl(gt, 63, 64);
    float lam = expf(gt);
    float beta = bf2f(betab[(size_t)(r0 + lane) * 32 + hv]);
    Gs[lane] = gt; Ls[lane] = lam;
    SCs[lane] = expf(GC - gt);
    BLs[lane] = beta;
    unsigned short* vb16 = (unsigned short*)(vecs + (size_t)bhc * 272);
    vb16[lane] = f2bf(beta * lam);   // beta*Lambda
    vb16[64 + lane] = f2bf(lam);     // Lambda
    if (lane == 0) *(float*)(vecs + (size_t)bhc * 272 + 256) = expf(GC);
  }
  // step 1: stage K,Q
  const unsigned short* Kg = conv + (size_t)r0 * 8192 + 2048 + hk * 128;
  const unsigned short* Qg = conv + (size_t)r0 * 8192 + hk * 128;
  for (int u = tid; u < 1024; u += 256) {
    int row = u >> 4, col = (u & 15) * 8;
    *(uint4*)(&Kb[row * 136 + col]) = *(const uint4*)(Kg + (size_t)row * 8192 + col);
    *(uint4*)(&Qb[row * 136 + col]) = *(const uint4*)(Qg + (size_t)row * 8192 + col);
  }
  __syncthreads();

  // step 2: KK^T and QK^T (wave w: rows w*16), write A (f32) and Pb (bf16)
  {
    f32x4 akk[4], aqk[4];
    #pragma unroll
    for (int st = 0; st < 4; st++) { akk[st] = f32x4{0,0,0,0}; aqk[st] = f32x4{0,0,0,0}; }
    int trow = wv * 16 + (lane & 15);
    int klo = (lane >> 4) * 8;
    #pragma unroll
    for (int ks = 0; ks < 4; ks++) {
      int ko = ks * 32 + klo;
      bf16x8 ak = *(const bf16x8*)(&Kb[trow * 136 + ko]);
      bf16x8 aq = *(const bf16x8*)(&Qb[trow * 136 + ko]);
      #pragma unroll
      for (int st = 0; st < 4; st++) {
        bf16x8 bk = *(const bf16x8*)(&Kb[(st * 16 + (lane & 15)) * 136 + ko]);
        akk[st] = MFMA(ak, bk, akk[st]);
        aqk[st] = MFMA(aq, bk, aqk[st]);
      }
    }
    int orow = wv * 16 + (lane >> 4) * 4;
    int oc = lane & 15;
    #pragma unroll
    for (int st = 0; st < 4; st++)
      #pragma unroll
      for (int r = 0; r < 4; r++) {
        int t = orow + r, ssv = st * 16 + oc;
        float e = expf(fminf(Gs[t] - Gs[ssv], 0.f));
        Ab[t * CPAD + ssv] = (ssv < t) ? BLs[t] * e * akk[st][r] : (ssv == t ? 1.f : 0.f);
        Pb[t * 72 + ssv] = f2bf((ssv <= t) ? e * aqk[st][r] : 0.f);
      }
  }
  __syncthreads();

  // step 3: KT build (scaled by SCs): Kb [64][136] -> [128][72]
  {
    unsigned short ktv[32];
    int dk = tid >> 1, tb = (tid & 1) * 32;
    #pragma unroll
    for (int i = 0; i < 32; i++)
      ktv[i] = f2bf(bf2f(Kb[(tb + i) * 136 + dk]) * SCs[tb + i]);
    __syncthreads();
    #pragma unroll
    for (int i = 0; i < 32; i++) Kb[dk * 72 + tb + i] = ktv[i];
  }
  __syncthreads();

  // step 4: invert (I+L) via forward substitution, stored transposed: XT[col][t]
  float* XT = (float*)Qb;
  if (wv == 0) {
    XT[lane * CPAD + 0] = (lane == 0) ? 1.f : 0.f;
    for (int t = 1; t < 64; t++) {
      float a0 = 0.f, a1 = 0.f, a2 = 0.f, a3 = 0.f;
      int sI = 0;
      for (; sI + 4 <= t; sI += 4) {
        a0 = fmaf(Ab[t * CPAD + sI],     XT[lane * CPAD + sI],     a0);
        a1 = fmaf(Ab[t * CPAD + sI + 1], XT[lane * CPAD + sI + 1], a1);
        a2 = fmaf(Ab[t * CPAD + sI + 2], XT[lane * CPAD + sI + 2], a2);
        a3 = fmaf(Ab[t * CPAD + sI + 3], XT[lane * CPAD + sI + 3], a3);
      }
      for (; sI < t; sI++) a0 = fmaf(Ab[t * CPAD + sI], XT[lane * CPAD + sI], a0);
      XT[lane * CPAD + t] = ((lane == t) ? 1.f : 0.f) - (a0 + a1 + (a2 + a3));
    }
  }
  __syncthreads();

  // step 5: XTb bf16 [64][72] over Ab
  unsigned short* XTb = (unsigned short*)Ab;
  for (int e = tid; e < 4096; e += 256) {
    int j = e >> 6, sI = e & 63;
    XTb[j * 72 + sI] = f2bf(XT[j * CPAD + sI]);
  }
  __syncthreads();

  // step 6: M1 = Pb@Tinv (16 tiles), M2 = KT@Tinv (32 tiles); 12 tiles/wave
  for (int tt = wv * 12; tt < wv * 12 + 12; tt++) {
    f32x4 acc = f32x4{0, 0, 0, 0};
    const unsigned short* Abase;
    int mrow, jc;
    if (tt < 16) { mrow = (tt >> 2) * 16; jc = (tt & 3) * 16; Abase = Pb + mrow * 72; }
    else { int i2 = tt - 16; mrow = (i2 >> 2) * 16; jc = (i2 & 3) * 16; Abase = Kb + mrow * 72; }
    #pragma unroll
    for (int ks = 0; ks < 2; ks++) {
      int so = ks * 32 + (lane >> 4) * 8;
      bf16x8 af = *(const bf16x8*)(Abase + (lane & 15) * 72 + so);
      bf16x8 bfv = *(const bf16x8*)(XTb + (jc + (lane & 15)) * 72 + so);
      acc = MFMA(af, bfv, acc);
    }
    int ro = mrow + (lane >> 4) * 4, co = jc + (lane & 15);
    if (tt < 16) {
      #pragma unroll
      for (int r = 0; r < 4; r++)
        M1g[(size_t)bhc * 4096 + (ro + r) * 64 + co] = f2bf(acc[r]);
    } else {
      #pragma unroll
      for (int r = 0; r < 4; r++)
        M2g[(size_t)bhc * 8192 + (ro + r) * 64 + co] = f2bf(acc[r]);
    }
  }
}

// ---------------- sequential chunk recurrence ----------------
// grid (4 dv-slices of 32, 64 bh); block 512 (8 waves)
__global__ __launch_bounds__(512) void seq_kernel(unsigned short* __restrict__ conv,
                                                  const unsigned short* __restrict__ M1g,
                                                  const unsigned short* __restrict__ M2g,
                                                  const unsigned char* __restrict__ vecs,
                                                  const unsigned short* __restrict__ betab) {
  const int dvs = blockIdx.x, bh = blockIdx.y;
  const int b = bh >> 5, hv = bh & 31, hk = hv >> 1;
  const int dv0 = dvs * 32;
  const int tid = threadIdx.x, lane = tid & 63, wv = tid >> 6;

  __shared__ unsigned short Kb[64 * 136], Qb[64 * 136];
  __shared__ float Sf[128 * 36];
  __shared__ unsigned short S0T[32 * 136];
  __shared__ unsigned short rhsT[32 * 72];

  for (int i = tid; i < 128 * 36; i += 512) Sf[i] = 0.f;
  for (int i = tid; i < 32 * 136; i += 512) S0T[i] = 0;
  __syncthreads();

  const int l15 = lane & 15, l4 = lane >> 4;
  const int trt = (wv >> 1) * 16;   // t-tile base
  const int tct = (wv & 1) * 16;    // dv-tile base

  for (int c = 0; c < 32; c++) {
    const int r0 = b * T_LEN + c * 64;
    const int bhc = bh * 32 + c;
    const unsigned char* vb = vecs + (size_t)bhc * 272;
    const unsigned short* vb16 = (const unsigned short*)vb;
    // stage K, Qhat (= Lambda_t * q_t)
    #pragma unroll
    for (int j = 0; j < 2; j++) {
      int u = tid * 2 + j;
      int row = u >> 4, col = (u & 15) * 8;
      uint4 kv = *(const uint4*)(conv + (size_t)(r0 + row) * 8192 + 2048 + hk * 128 + col);
      uint4 qv = *(const uint4*)(conv + (size_t)(r0 + row) * 8192 + hk * 128 + col);
      *(uint4*)(&Kb[row * 136 + col]) = kv;
      float lam = bf2f(vb16[64 + row]);
      union { uint4 u4; unsigned short h[8]; } qq; qq.u4 = qv;
      #pragma unroll
      for (int e = 0; e < 8; e++) qq.h[e] = f2bf(bf2f(qq.h[e]) * lam);
      *(uint4*)(&Qb[row * 136 + col]) = qq.u4;
    }
    __syncthreads();
    // KS0 -> rhs -> rhsT
    {
      f32x4 acc = f32x4{0, 0, 0, 0};
      #pragma unroll
      for (int ks = 0; ks < 4; ks++) {
        int ko = ks * 32 + l4 * 8;
        bf16x8 af = *(const bf16x8*)(&Kb[(trt + l15) * 136 + ko]);
        bf16x8 bfv = *(const bf16x8*)(&S0T[(tct + l15) * 136 + ko]);
        acc = MFMA(af, bfv, acc);
      }
      #pragma unroll
      for (int r = 0; r < 4; r++) {
        int tl = trt + l4 * 4 + r;
        int t = r0 + tl;
        float beta = bf2f(betab[(size_t)t * 32 + hv]);
        float bl = bf2f(vb16[tl]);
        float vv = bf2f(conv[(size_t)t * 8192 + 4096 + hv * 128 + dv0 + tct + l15]);
        rhsT[(tct + l15) * 72 + tl] = f2bf(beta * vv - bl * acc[r]);
      }
    }
    __syncthreads();
    // O = M1@rhsT + Qhat@S0T -> write o over v
    {
      f32x4 acc = f32x4{0, 0, 0, 0};
      const unsigned short* m1b = M1g + (size_t)bhc * 4096;
      #pragma unroll
      for (int ks = 0; ks < 2; ks++) {
        int so = ks * 32 + l4 * 8;
        union { uint4 u4; bf16x8 h; } af;
        af.u4 = *(const uint4*)(m1b + (trt + l15) * 64 + so);
        bf16x8 bfv = *(const bf16x8*)(&rhsT[(tct + l15) * 72 + so]);
        acc = MFMA(af.h, bfv, acc);
      }
      #pragma unroll
      for (int ks = 0; ks < 4; ks++) {
        int ko = ks * 32 + l4 * 8;
        bf16x8 af = *(const bf16x8*)(&Qb[(trt + l15) * 136 + ko]);
        bf16x8 bfv = *(const bf16x8*)(&S0T[(tct + l15) * 136 + ko]);
        acc = MFMA(af, bfv, acc);
      }
      #pragma unroll
      for (int r = 0; r < 4; r++) {
        int t = r0 + trt + l4 * 4 + r;
        conv[(size_t)t * 8192 + 4096 + hv * 128 + dv0 + tct + l15] = f2bf(acc[r]);
      }
    }
    // S = LambdaC*S0 + M2@rhsT
    {
      float lamC = *(const float*)(vb + 256);
      f32x4 sacc[2];
      const unsigned short* m2b = M2g + (size_t)bhc * 8192;
      const int dkb = wv * 16;
      #pragma unroll
      for (int dt = 0; dt < 2; dt++) {
        int dvb = dt * 16;
        f32x4 a;
        #pragma unroll
        for (int r = 0; r < 4; r++) a[r] = lamC * Sf[(dkb + l4 * 4 + r) * 36 + dvb + l15];
        #pragma unroll
        for (int ks = 0; ks < 2; ks++) {
          int so = ks * 32 + l4 * 8;
          union { uint4 u4; bf16x8 h; } af;
          af.u4 = *(const uint4*)(m2b + (dkb + l15) * 64 + so);
          bf16x8 bfv = *(const bf16x8*)(&rhsT[(dvb + l15) * 72 + so]);
          a = MFMA(af.h, bfv, a);
        }
        sacc[dt] = a;
      }
      __syncthreads();   // all reads of S0T/Sf/rhsT complete
      #pragma unroll
      for (int dt = 0; dt < 2; dt++) {
        int dvb = dt * 16;
        #pragma unroll
        for (int r = 0; r < 4; r++) {
          int dk = dkb + l4 * 4 + r, dvl = dvb + l15;
          Sf[dk * 36 + dvl] = sacc[dt][r];
          S0T[dvl * 136 + dk] = f2bf(sacc[dt][r]);
        }
      }
    }
    __syncthreads();
  }
}

// ---------------- gated RMSNorm in-place on o (in conv_out V-section) ----------------
__global__ __launch_bounds__(256) void rmsgate_kernel(unsigned short* __restrict__ conv,
                                                      const unsigned short* __restrict__ zg,
                                                      const float* __restrict__ nw) {
  int wid = blockIdx.x * 4 + (threadIdx.x >> 6);
  int lane = threadIdx.x & 63;
  int row = wid >> 5, hv = wid & 31;
  unsigned short* op = conv + (size_t)row * 8192 + 4096 + hv * 128;
  float o0 = bf2f(op[lane]), o1 = bf2f(op[64 + lane]);
  float ss = o0 * o0 + o1 * o1;
  #pragma unroll
  for (int m = 1; m < 64; m <<= 1) ss += __shfl_xor(ss, m);
  float r = rsqrtf(ss * (1.f / 128.f) + 1e-6f);
  const unsigned short* zp = zg + (size_t)row * 4096 + hv * 128;
  float g0 = bf2f(zp[lane]), g1 = bf2f(zp[64 + lane]);
  g0 = g0 / (1.f + expf(-g0));
  g1 = g1 / (1.f + expf(-g1));
  op[lane] = f2bf(o0 * r * g0 * nw[lane]);
  op[64 + lane] = f2bf(o1 * r * g1 * nw[64 + lane]);
}

extern "C" void kernel_launch(void* const* d_in, const int* in_sizes, int n_in,
                              void* d_out, int out_size, void* d_ws, size_t ws_size,
                              hipStream_t stream) {
  (void)in_sizes; (void)n_in; (void)out_size;
  const float* x       = (const float*)d_in[0];
  const float* W_qkv   = (const float*)d_in[1];
  const float* W_z     = (const float*)d_in[2];
  const float* W_b     = (const float*)d_in[3];
  const float* W_a     = (const float*)d_in[4];
  const float* conv_w  = (const float*)d_in[5];
  const float* dt_bias = (const float*)d_in[6];
  const float* A_log   = (const float*)d_in[7];
  const float* nw      = (const float*)d_in[8];
  const float* W_out   = (const float*)d_in[9];
  float* out = (float*)d_out;

  const size_t NEED = 169115648ULL;   // <= 169,345,024 proven in round 2
  if (ws_size < NEED) return;

  char* ws = (char*)d_ws;
  // slot0 @0 (64MiB): qkv_bf -> {M1, M2} -> WoutT over M1
  unsigned short* qkv_bf = (unsigned short*)(ws + 0);
  unsigned short* M1g    = (unsigned short*)(ws + 0);
  unsigned short* M2g    = (unsigned short*)(ws + 16777216);
  unsigned short* WoutT  = (unsigned short*)(ws + 0);
  // zg @64MiB (32MiB)
  unsigned short* zg     = (unsigned short*)(ws + 67108864);
  // slot2 @96MiB (64MiB): {WzT, x_bf, WqkvT/(WbaT,ba)} -> conv_out
  unsigned short* WzT    = (unsigned short*)(ws + 100663296);
  unsigned short* x_bf   = (unsigned short*)(ws + 100663296 + 16777216);
  unsigned short* WqkvT  = (unsigned short*)(ws + 100663296 + 33554432);
  unsigned short* WbaT   = (unsigned short*)(ws + 100663296 + 33554432);
  unsigned short* ba     = (unsigned short*)(ws + 100663296 + 34078720);
  unsigned short* convb  = (unsigned short*)(ws + 100663296);
  // tail @160MiB
  unsigned short* betab  = (unsigned short*)(ws + 167772160);
  float* gbuf            = (float*)(ws + 168034304);
  unsigned char* vecs    = (unsigned char*)(ws + 168558592);

  const int M = MROWS;

  // 1) conversions + big weight transposes
  f32_to_bf16_vec<<<(M * 2048 / 4) / 256, 256, 0, stream>>>(x, x_bf, M * 2048 / 4);
  transpose_f2b<<<dim3(8192 / 32, 2048 / 32), 256, 0, stream>>>(W_qkv, WqkvT, 2048, 8192);
  transpose_f2b<<<dim3(4096 / 32, 2048 / 32), 256, 0, stream>>>(W_z, WzT, 2048, 4096);

  // 2) GEMM1 -> qkv_bf
  gemm_bf16<1><<<dim3(8192 / 128, M / 128), 256, 0, stream>>>(x_bf, 2048, WqkvT, 2048, qkv_bf, 8192, M, 8192, 2048);

  // 3) small b/a weight transposes (over WqkvT, dead after GEMM1)
  transpose_f2b<<<dim3(1, 64), 256, 0, stream>>>(W_b, WbaT, 2048, 32);
  transpose_f2b<<<dim3(1, 64), 256, 0, stream>>>(W_a, WbaT + (size_t)32 * 2048, 2048, 32);

  // 4) GEMM2a -> zg ; GEMM2b -> ba
  gemm_bf16<1><<<dim3(4096 / 128, M / 128), 256, 0, stream>>>(x_bf, 2048, WzT, 2048, zg, 4096, M, 4096, 2048);
  gemm_bf16<1><<<dim3(1, M / 128), 256, 0, stream>>>(x_bf, 2048, WbaT, 2048, ba, 128, M, 128, 2048);

  // 5) beta/g (into tail; survives conv overwrite of slot2)
  beta_g_kernel<<<(M * 32) / 256, 256, 0, stream>>>(ba, A_log, dt_bias, betab, gbuf);

  // 6) conv -> conv_out (overwrites slot2; x_bf/WzT/WbaT/ba dead)
  conv_kernel<<<dim3(64, 64, 2), 256, 0, stream>>>(qkv_bf, conv_w, convb);

  // 7) precompute M1/M2/vecs (over qkv_bf, dead after conv)
  prep_kernel<<<dim3(32, 64), 256, 0, stream>>>(convb, gbuf, betab, M1g, M2g, vecs);

  // 8) sequential chunk recurrence; o overwrites conv_out V-section
  seq_kernel<<<dim3(4, 64), 512, 0, stream>>>(convb, M1g, M2g, vecs, betab);

  // 9) gated RMSNorm in place on o
  rmsgate_kernel<<<32768, 256, 0, stream>>>(convb, zg, nw);

  // 10) W_out transpose (over M1, dead) + final GEMM -> f32 out
  transpose_f2b<<<dim3(2048 / 32, 4096 / 32), 256, 0, stream>>>(W_out, WoutT, 4096, 2048);
  gemm_bf16<0><<<dim3(2048 / 128, M / 128), 256, 0, stream>>>(convb + 4096, 8192, WoutT, 4096, out, 2048, M, 2048, 4096);
}

// Round 4
// 718.758 us; speedup vs baseline: 2.8852x; 1.1661x over previous
//
#include <hip/hip_runtime.h>

// Qwen3.5 GatedDeltaNet fwd on gfx950 — chunked delta-rule + 256^2 counted-vmcnt GEMM.
// B=2 T=2048 HID=2048 HK=16 HV=32 DK=DV=128 KW=4, chunk C=64 (32 chunks).

#define T_LEN 2048
#define MROWS 4096
#define CPAD 65

typedef __bf16 bf16x8 __attribute__((ext_vector_type(8)));
typedef float f32x4 __attribute__((ext_vector_type(4)));

#define MFMA(a, b, c) __builtin_amdgcn_mfma_f32_16x16x32_bf16((a), (b), (c), 0, 0, 0)

__device__ __forceinline__ unsigned short f2bf(float f) {
  unsigned int u = __float_as_uint(f);
  unsigned int r = (u + 0x7fffu + ((u >> 16) & 1u)) >> 16;
  return (unsigned short)r;
}
__device__ __forceinline__ float bf2f(unsigned short u) {
  return __uint_as_float(((unsigned int)u) << 16);
}
__device__ __forceinline__ void gload_lds16(const void* g, void* l) {
  __builtin_amdgcn_global_load_lds(
      (const __attribute__((address_space(1))) unsigned int*)g,
      (__attribute__((address_space(3))) unsigned int*)l, 16, 0, 0);
}

// ---------------- elementwise f32 -> bf16 ----------------
__global__ __launch_bounds__(256) void f32_to_bf16_vec(const float* __restrict__ src,
                                                       unsigned short* __restrict__ dst,
                                                       int n4) {
  int i = blockIdx.x * 256 + threadIdx.x;
  if (i >= n4) return;
  float4 v = ((const float4*)src)[i];
  ushort4 o;
  o.x = f2bf(v.x); o.y = f2bf(v.y); o.z = f2bf(v.z); o.w = f2bf(v.w);
  ((ushort4*)dst)[i] = o;
}

// ---------------- transpose f32 [R,C] -> bf16 [C,R] ----------------
__global__ __launch_bounds__(256) void transpose_f2b(const float* __restrict__ src,
                                                     unsigned short* __restrict__ dst,
                                                     int R, int C) {
  __shared__ float tile[32][33];
  int tx = threadIdx.x & 31, ty = threadIdx.x >> 5;
  int c0 = blockIdx.x * 32, r0 = blockIdx.y * 32;
  #pragma unroll
  for (int i = ty; i < 32; i += 8)
    tile[i][tx] = src[(size_t)(r0 + i) * C + c0 + tx];
  __syncthreads();
  #pragma unroll
  for (int i = ty; i < 32; i += 8)
    dst[(size_t)(c0 + i) * R + r0 + tx] = f2bf(tile[tx][i]);
}

// ===================== 256-wide-tile GEMM, counted-vmcnt pipeline =====================
// C[M,N] = A[M,K](lda) @ Bt[N,K](ldb)^T. BM=256, BN=256 or 128, BK=64, 512 thr (8 waves).
// LDS: 2 buffers x (A 32KB + B BN*128B), st-swizzle byte^=(row&7)<<4 on src+read.
// Pipeline per tile t: compute(t) -> s_barrier -> STAGE(t+2) -> vmcnt(IS) -> s_barrier.
template <int OUTBF, int BN>
__global__ __launch_bounds__(512, 2) void gemm256(const unsigned short* __restrict__ A, int lda,
                                                  const unsigned short* __restrict__ Bt, int ldb,
                                                  void* __restrict__ Cv, int ldc,
                                                  int M, int N, int K) {
  constexpr int BUFSZ = 16384 + BN * 64;     // ushorts per buffer
  constexpr int BISS = BN / 64;              // B gload issues per tile
  constexpr int IS = 4 + BISS;               // total gload issues per tile
  constexpr int WMv = (BN == 256) ? 2 : 4;   // waves along M
  constexpr int MSUB = 256 / (WMv * 16);     // M subtiles per wave
  constexpr int MSPAN = 256 / WMv;           // rows per wave

  __shared__ unsigned short lds[2 * BUFSZ];

  const int mtiles = M >> 8;
  const int nwg = gridDim.x;
  const int orig = blockIdx.x;
  const int q = nwg >> 3, r = nwg & 7;
  const int xcd = orig & 7, idx = orig >> 3;
  const int swz = (xcd < r ? xcd * (q + 1) : r * (q + 1) + (xcd - r) * q) + idx;
  const int m0 = (swz % mtiles) * 256;
  const int n0 = (swz / mtiles) * BN;

  const int tid = threadIdx.x, lane = tid & 63, wv = tid >> 6;
  const int wm = (BN == 256) ? (wv >> 2) : (wv >> 1);
  const int wn = (BN == 256) ? (wv & 3) : (wv & 1);
  const int l15 = lane & 15, l4 = lane >> 4;

  f32x4 acc[MSUB][4];
  #pragma unroll
  for (int i = 0; i < MSUB; i++)
    #pragma unroll
    for (int j = 0; j < 4; j++) acc[i][j] = f32x4{0.f, 0.f, 0.f, 0.f};

  const int NT = K >> 6;

  auto STAGE = [&](int kt) {
    unsigned short* base = lds + (kt & 1) * BUFSZ;
    const int k0 = kt << 6;
    #pragma unroll
    for (int is = 0; is < 4; is++) {
      int ow = is * 8192 + wv * 1024;           // wave-uniform dest byte offset
      int o = ow + lane * 16;                   // this lane's logical byte
      int row = o >> 7, colB = o & 127;
      int scol = colB ^ ((row & 7) << 4);
      gload_lds16(A + (size_t)(m0 + row) * lda + k0 + (scol >> 1), base + (ow >> 1));
    }
    #pragma unroll
    for (int is = 0; is < BISS; is++) {
      int ow = is * 8192 + wv * 1024;
      int o = ow + lane * 16;
      int row = o >> 7, colB = o & 127;
      int scol = colB ^ ((row & 7) << 4);
      gload_lds16(Bt + (size_t)(n0 + row) * ldb + k0 + (scol >> 1), base + 16384 + (ow >> 1));
    }
  };

  STAGE(0);
  if (NT > 1) STAGE(1);
  if constexpr (IS == 8) asm volatile("s_waitcnt vmcnt(8)" ::: "memory");
  else                   asm volatile("s_waitcnt vmcnt(6)" ::: "memory");
  __builtin_amdgcn_sched_barrier(0);
  __builtin_amdgcn_s_barrier();
  __builtin_amdgcn_sched_barrier(0);

  for (int t = 0; t < NT; t++) {
    const unsigned short* Abuf = lds + (t & 1) * BUFSZ;
    const unsigned short* Bbuf = Abuf + 16384;
    // B fragments (read once per tile)
    bf16x8 bF[4][2];
    #pragma unroll
    for (int n = 0; n < 4; n++) {
      int rb = wn * 64 + n * 16 + l15;
      int sw = (rb & 7) << 4;
      #pragma unroll
      for (int ks = 0; ks < 2; ks++) {
        int colB = (ks * 32 + l4 * 8) * 2;
        bF[n][ks] = *(const bf16x8*)(Bbuf + rb * 64 + ((colB ^ sw) >> 1));
      }
    }
    __builtin_amdgcn_s_setprio(1);
    #pragma unroll
    for (int m = 0; m < MSUB; m++) {
      int ra = wm * MSPAN + m * 16 + l15;
      int sw = (ra & 7) << 4;
      int c0b = l4 * 16;
      bf16x8 a0 = *(const bf16x8*)(Abuf + ra * 64 + ((c0b ^ sw) >> 1));
      bf16x8 a1 = *(const bf16x8*)(Abuf + ra * 64 + (((64 + c0b) ^ sw) >> 1));
      #pragma unroll
      for (int n = 0; n < 4; n++) {
        acc[m][n] = MFMA(a0, bF[n][0], acc[m][n]);
        acc[m][n] = MFMA(a1, bF[n][1], acc[m][n]);
      }
    }
    __builtin_amdgcn_s_setprio(0);
    __builtin_amdgcn_sched_barrier(0);
    __builtin_amdgcn_s_barrier();            // all reads of buf[t&1] done
    __builtin_amdgcn_sched_barrier(0);
    if (t + 2 < NT) STAGE(t + 2);            // overwrites buf[t&1]
    if (t + 1 < NT) {
      if (t + 2 < NT) {
        if constexpr (IS == 8) asm volatile("s_waitcnt vmcnt(8)" ::: "memory");
        else                   asm volatile("s_waitcnt vmcnt(6)" ::: "memory");
      } else {
        asm volatile("s_waitcnt vmcnt(0)" ::: "memory");
      }
      __builtin_amdgcn_sched_barrier(0);
      __builtin_amdgcn_s_barrier();          // buf[(t+1)&1] fully staged
      __builtin_amdgcn_sched_barrier(0);
    }
  }

  // epilogue
  #pragma unroll
  for (int m = 0; m < MSUB; m++) {
    int grow = m0 + wm * MSPAN + m * 16 + l4 * 4;
    #pragma unroll
    for (int n = 0; n < 4; n++) {
      int gcol = n0 + wn * 64 + n * 16 + l15;
      if (OUTBF) {
        unsigned short* cp = (unsigned short*)Cv + (size_t)grow * ldc + gcol;
        #pragma unroll
        for (int rr = 0; rr < 4; rr++) cp[(size_t)rr * ldc] = f2bf(acc[m][n][rr]);
      } else {
        float* cp = (float*)Cv + (size_t)grow * ldc + gcol;
        #pragma unroll
        for (int rr = 0; rr < 4; rr++) cp[(size_t)rr * ldc] = acc[m][n][rr];
      }
    }
  }
}

// ------- bf16 MFMA GEMM (128^2, small-N fallback): C[M,N] = A[M,K] @ Bt[N,K]^T -------
template <int OUTBF>
__global__ __launch_bounds__(256) void gemm_bf16(const unsigned short* __restrict__ A, int lda,
                                                 const unsigned short* __restrict__ Bt, int ldb,
                                                 void* __restrict__ Cv, int ldc,
                                                 int M, int N, int K) {
  __shared__ unsigned short As[128 * 64];
  __shared__ unsigned short Bs[128 * 64];
  const int tid = threadIdx.x, lane = tid & 63, wv = tid >> 6;
  const int wr = wv >> 1, wc = wv & 1;
  const int m0 = blockIdx.y * 128, n0 = blockIdx.x * 128;
  const int lrow8 = lane >> 3;
  const int lk8 = (lane & 7) * 8;

  f32x4 acc[4][4];
  #pragma unroll
  for (int i = 0; i < 4; i++)
    #pragma unroll
    for (int j = 0; j < 4; j++) acc[i][j] = f32x4{0.f, 0.f, 0.f, 0.f};

  for (int k0 = 0; k0 < K; k0 += 64) {
    #pragma unroll
    for (int j = 0; j < 4; ++j) {
      int chunk = j * 4 + wv;
      int r = chunk * 8 + lrow8;
      gload_lds16(A + (size_t)(m0 + r) * lda + k0 + lk8, (void*)(As + chunk * 512));
      gload_lds16(Bt + (size_t)(n0 + r) * ldb + k0 + lk8, (void*)(Bs + chunk * 512));
    }
    __syncthreads();
    #pragma unroll
    for (int half = 0; half < 2; ++half) {
      int ko = half * 32 + (lane >> 4) * 8;
      bf16x8 af[4], bfr[4];
      #pragma unroll
      for (int i = 0; i < 4; i++) {
        int ra = wr * 64 + i * 16 + (lane & 15);
        af[i] = *(const bf16x8*)(As + ra * 64 + ko);
        int rb = wc * 64 + i * 16 + (lane & 15);
        bfr[i] = *(const bf16x8*)(Bs + rb * 64 + ko);
      }
      #pragma unroll
      for (int i = 0; i < 4; i++)
        #pragma unroll
        for (int j = 0; j < 4; j++)
          acc[i][j] = MFMA(af[i], bfr[j], acc[i][j]);
    }
    __syncthreads();
  }
  int cr4 = (lane >> 4) * 4;
  int cc = lane & 15;
  #pragma unroll
  for (int i = 0; i < 4; i++) {
    int row = m0 + wr * 64 + i * 16 + cr4;
    #pragma unroll
    for (int j = 0; j < 4; j++) {
      int col = n0 + wc * 64 + j * 16 + cc;
      if (OUTBF) {
        unsigned short* cp = (unsigned short*)Cv + (size_t)row * ldc + col;
        #pragma unroll
        for (int r = 0; r < 4; r++) cp[(size_t)r * ldc] = f2bf(acc[i][j][r]);
      } else {
        float* cp = (float*)Cv + (size_t)row * ldc + col;
        #pragma unroll
        for (int r = 0; r < 4; r++) cp[(size_t)r * ldc] = acc[i][j][r];
      }
    }
  }
}

// ---------------- beta / g from ba (bf16 [4096][128]: cols 0-31 b, 32-63 a) ----------------
__global__ __launch_bounds__(256) void beta_g_kernel(const unsigned short* __restrict__ ba,
                                                     const float* __restrict__ A_log,
                                                     const float* __restrict__ dt_bias,
                                                     unsigned short* __restrict__ betab,
                                                     float* __restrict__ g) {
  int i = blockIdx.x * 256 + threadIdx.x;  // row*32+hv, rows=4096
  int row = i >> 5, hv = i & 31;
  float rb = bf2f(ba[(size_t)row * 128 + hv]);
  float ra = bf2f(ba[(size_t)row * 128 + 32 + hv]);
  betab[i] = f2bf(1.f / (1.f + expf(-rb)));
  float xg = ra + dt_bias[hv];
  float sp = (xg > 20.f) ? xg : log1pf(expf(xg));
  g[i] = -expf(A_log[hv]) * sp;
}

// ------- conv4 + SiLU + q/k l2norm (permutes to mixed layout), bf16 in/out -------
// grid (64 segs, 64 t-tiles, 2 b); block 256
__global__ __launch_bounds__(256) void conv_kernel(const unsigned short* __restrict__ qkv,
                                                   const float* __restrict__ conv_w,
                                                   unsigned short* __restrict__ out) {
  const int seg = blockIdx.x, tt = blockIdx.y, b = blockIdx.z;
  const int tid = threadIdx.x;
  const int c0 = seg * 128;
  const bool isq = seg < 16;
  int scb;
  if (isq) scb = seg * 512;
  else if (seg < 32) scb = (seg - 16) * 512 + 128;
  else scb = ((seg - 32) >> 1) * 512 + 256 + ((seg - 32) & 1) * 128;

  __shared__ unsigned short raw[35][136];
  __shared__ float cw[4][132];

  for (int i = tid; i < 512; i += 256) {
    int cl = i >> 2, tap = i & 3;
    cw[tap][cl] = conv_w[(size_t)(c0 + cl) * 4 + tap];
  }
  const int t0 = tt * 32;
  for (int i = tid; i < 560; i += 256) {   // 35 rows x 16 uint4
    int row = i >> 4, col = (i & 15) * 8;
    int gt = t0 - 3 + row;
    uint4 v = make_uint4(0u, 0u, 0u, 0u);
    if (gt >= 0) v = *(const uint4*)(qkv + (size_t)(b * T_LEN + gt) * 8192 + scb + col);
    *(uint4*)(&raw[row][col]) = v;
  }
  __syncthreads();
  const int s = tid >> 3, dg = tid & 7;
  union RawU { uint4 v[2]; unsigned short h[16]; };
  RawU u[4];
  #pragma unroll
  for (int i = 0; i < 4; i++) {
    const uint4* p = (const uint4*)&raw[s + i][dg * 16];
    u[i].v[0] = p[0]; u[i].v[1] = p[1];
  }
  float vals[16]; float ss = 0.f;
  #pragma unroll
  for (int j = 0; j < 16; j++) {
    float a = 0.f;
    #pragma unroll
    for (int i = 0; i < 4; i++) a = fmaf(cw[i][dg * 16 + j], bf2f(u[i].h[j]), a);
    a = a / (1.f + expf(-a));
    vals[j] = a; ss += a * a;
  }
  if (seg < 32) {
    ss += __shfl_xor(ss, 1); ss += __shfl_xor(ss, 2); ss += __shfl_xor(ss, 4);
    float sc = rsqrtf(ss + 1e-6f);
    if (isq) sc *= 0.08838834764831845f;  // DK^-0.5
    #pragma unroll
    for (int j = 0; j < 16; j++) vals[j] *= sc;
  }
  union { uint4 v[2]; unsigned short h[16]; } ov;
  #pragma unroll
  for (int j = 0; j < 16; j++) ov.h[j] = f2bf(vals[j]);
  unsigned short* op = out + (size_t)(b * T_LEN + t0 + s) * 8192 + c0 + dg * 16;
  *(uint4*)(op) = ov.v[0];
  *(uint4*)(op + 8) = ov.v[1];
}

// ---------------- prep: per chunk-head precompute M1, M2, vecs ----------------
// grid (32 chunks, 64 bh); block 256 (4 waves)
__global__ __launch_bounds__(256) void prep_kernel(const unsigned short* __restrict__ conv,
                                                   const float* __restrict__ g,
                                                   const unsigned short* __restrict__ betab,
                                                   unsigned short* __restrict__ M1g,
                                                   unsigned short* __restrict__ M2g,
                                                   unsigned char* __restrict__ vecs) {
  const int c = blockIdx.x, bh = blockIdx.y;
  const int b = bh >> 5, hv = bh & 31, hk = hv >> 1;
  const int bhc = bh * 32 + c;
  const int tid = threadIdx.x, lane = tid & 63, wv = tid >> 6;
  const int r0 = b * T_LEN + c * 64;

  __shared__ unsigned short Kb[128 * 72];   // K [64][136] then KT [128][72]
  __shared__ unsigned short Qb[64 * 136];   // Q then XT f32 [64][65]
  __shared__ float Ab[64 * CPAD];           // A f32, later XTb bf16 [64][72]
  __shared__ unsigned short Pb[64 * 72];
  __shared__ float Gs[64], Ls[64], SCs[64], BLs[64];

  // step 0: decay prefix + vecs (wave 0)
  if (wv == 0) {
    float gt = g[(size_t)(r0 + lane) * 32 + hv];
    #pragma unroll
    for (int d = 1; d < 64; d <<= 1) {
      float o = __shfl_up(gt, (unsigned)d, 64);
      if (lane >= d) gt += o;
    }
    float GC = __shfl(gt, 63, 64);
    float lam = expf(gt);
    float beta = bf2f(betab[(size_t)(r0 + lane) * 32 + hv]);
    Gs[lane] = gt; Ls[lane] = lam;
    SCs[lane] = expf(GC - gt);
    BLs[lane] = beta;
    unsigned short* vb16 = (unsigned short*)(vecs + (size_t)bhc * 272);
    vb16[lane] = f2bf(beta * lam);   // beta*Lambda
    vb16[64 + lane] = f2bf(lam);     // Lambda
    if (lane == 0) *(float*)(vecs + (size_t)bhc * 272 + 256) = expf(GC);
  }
  // step 1: stage K,Q
  const unsigned short* Kg = conv + (size_t)r0 * 8192 + 2048 + hk * 128;
  const unsigned short* Qg = conv + (size_t)r0 * 8192 + hk * 128;
  for (int u = tid; u < 1024; u += 256) {
    int row = u >> 4, col = (u & 15) * 8;
    *(uint4*)(&Kb[row * 136 + col]) = *(const uint4*)(Kg + (size_t)row * 8192 + col);
    *(uint4*)(&Qb[row * 136 + col]) = *(const uint4*)(Qg + (size_t)row * 8192 + col);
  }
  __syncthreads();

  // step 2: KK^T and QK^T (wave w: rows w*16), write A (f32) and Pb (bf16)
  {
    f32x4 akk[4], aqk[4];
    #pragma unroll
    for (int st = 0; st < 4; st++) { akk[st] = f32x4{0,0,0,0}; aqk[st] = f32x4{0,0,0,0}; }
    int trow = wv * 16 + (lane & 15);
    int klo = (lane >> 4) * 8;
    #pragma unroll
    for (int ks = 0; ks < 4; ks++) {
      int ko = ks * 32 + klo;
      bf16x8 ak = *(const bf16x8*)(&Kb[trow * 136 + ko]);
      bf16x8 aq = *(const bf16x8*)(&Qb[trow * 136 + ko]);
      #pragma unroll
      for (int st = 0; st < 4; st++) {
        bf16x8 bk = *(const bf16x8*)(&Kb[(st * 16 + (lane & 15)) * 136 + ko]);
        akk[st] = MFMA(ak, bk, akk[st]);
        aqk[st] = MFMA(aq, bk, aqk[st]);
      }
    }
    int orow = wv * 16 + (lane >> 4) * 4;
    int oc = lane & 15;
    #pragma unroll
    for (int st = 0; st < 4; st++)
      #pragma unroll
      for (int r = 0; r < 4; r++) {
        int t = orow + r, ssv = st * 16 + oc;
        float e = expf(fminf(Gs[t] - Gs[ssv], 0.f));
        Ab[t * CPAD + ssv] = (ssv < t) ? BLs[t] * e * akk[st][r] : (ssv == t ? 1.f : 0.f);
        Pb[t * 72 + ssv] = f2bf((ssv <= t) ? e * aqk[st][r] : 0.f);
      }
  }
  __syncthreads();

  // step 3: KT build (scaled by SCs): Kb [64][136] -> [128][72]
  {
    unsigned short ktv[32];
    int dk = tid >> 1, tb = (tid & 1) * 32;
    #pragma unroll
    for (int i = 0; i < 32; i++)
      ktv[i] = f2bf(bf2f(Kb[(tb + i) * 136 + dk]) * SCs[tb + i]);
    __syncthreads();
    #pragma unroll
    for (int i = 0; i < 32; i++) Kb[dk * 72 + tb + i] = ktv[i];
  }
  __syncthreads();

  // step 4: invert (I+L) via forward substitution, stored transposed: XT[col][t]
  float* XT = (float*)Qb;
  if (wv == 0) {
    XT[lane * CPAD + 0] = (lane == 0) ? 1.f : 0.f;
    for (int t = 1; t < 64; t++) {
      float a0 = 0.f, a1 = 0.f, a2 = 0.f, a3 = 0.f;
      int sI = 0;
      for (; sI + 4 <= t; sI += 4) {
        a0 = fmaf(Ab[t * CPAD + sI],     XT[lane * CPAD + sI],     a0);
        a1 = fmaf(Ab[t * CPAD + sI + 1], XT[lane * CPAD + sI + 1], a1);
        a2 = fmaf(Ab[t * CPAD + sI + 2], XT[lane * CPAD + sI + 2], a2);
        a3 = fmaf(Ab[t * CPAD + sI + 3], XT[lane * CPAD + sI + 3], a3);
      }
      for (; sI < t; sI++) a0 = fmaf(Ab[t * CPAD + sI], XT[lane * CPAD + sI], a0);
      XT[lane * CPAD + t] = ((lane == t) ? 1.f : 0.f) - (a0 + a1 + (a2 + a3));
    }
  }
  __syncthreads();

  // step 5: XTb bf16 [64][72] over Ab
  unsigned short* XTb = (unsigned short*)Ab;
  for (int e = tid; e < 4096; e += 256) {
    int j = e >> 6, sI = e & 63;
    XTb[j * 72 + sI] = f2bf(XT[j * CPAD + sI]);
  }
  __syncthreads();

  // step 6: M1 = Pb@Tinv (16 tiles), M2 = KT@Tinv (32 tiles); 12 tiles/wave
  for (int tt = wv * 12; tt < wv * 12 + 12; tt++) {
    f32x4 acc = f32x4{0, 0, 0, 0};
    const unsigned short* Abase;
    int mrow, jc;
    if (tt < 16) { mrow = (tt >> 2) * 16; jc = (tt & 3) * 16; Abase = Pb + mrow * 72; }
    else { int i2 = tt - 16; mrow = (i2 >> 2) * 16; jc = (i2 & 3) * 16; Abase = Kb + mrow * 72; }
    #pragma unroll
    for (int ks = 0; ks < 2; ks++) {
      int so = ks * 32 + (lane >> 4) * 8;
      bf16x8 af = *(const bf16x8*)(Abase + (lane & 15) * 72 + so);
      bf16x8 bfv = *(const bf16x8*)(XTb + (jc + (lane & 15)) * 72 + so);
      acc = MFMA(af, bfv, acc);
    }
    int ro = mrow + (lane >> 4) * 4, co = jc + (lane & 15);
    if (tt < 16) {
      #pragma unroll
      for (int r = 0; r < 4; r++)
        M1g[(size_t)bhc * 4096 + (ro + r) * 64 + co] = f2bf(acc[r]);
    } else {
      #pragma unroll
      for (int r = 0; r < 4; r++)
        M2g[(size_t)bhc * 8192 + (ro + r) * 64 + co] = f2bf(acc[r]);
    }
  }
}

// ---------------- sequential chunk recurrence ----------------
// grid (4 dv-slices of 32, 64 bh); block 512 (8 waves)
__global__ __launch_bounds__(512) void seq_kernel(unsigned short* __restrict__ conv,
                                                  const unsigned short* __restrict__ M1g,
                                                  const unsigned short* __restrict__ M2g,
                                                  const unsigned char* __restrict__ vecs,
                                                  const unsigned short* __restrict__ betab) {
  const int dvs = blockIdx.x, bh = blockIdx.y;
  const int b = bh >> 5, hv = bh & 31, hk = hv >> 1;
  const int dv0 = dvs * 32;
  const int tid = threadIdx.x, lane = tid & 63, wv = tid >> 6;

  __shared__ unsigned short Kb[64 * 136], Qb[64 * 136];
  __shared__ float Sf[128 * 36];
  __shared__ unsigned short S0T[32 * 136];
  __shared__ unsigned short rhsT[32 * 72];

  for (int i = tid; i < 128 * 36; i += 512) Sf[i] = 0.f;
  for (int i = tid; i < 32 * 136; i += 512) S0T[i] = 0;
  __syncthreads();

  const int l15 = lane & 15, l4 = lane >> 4;
  const int trt = (wv >> 1) * 16;   // t-tile base
  const int tct = (wv & 1) * 16;    // dv-tile base

  for (int c = 0; c < 32; c++) {
    const int r0 = b * T_LEN + c * 64;
    const int bhc = bh * 32 + c;
    const unsigned char* vb = vecs + (size_t)bhc * 272;
    const unsigned short* vb16 = (const unsigned short*)vb;
    // stage K, Qhat (= Lambda_t * q_t)
    #pragma unroll
    for (int j = 0; j < 2; j++) {
      int u = tid * 2 + j;
      int row = u >> 4, col = (u & 15) * 8;
      uint4 kv = *(const uint4*)(conv + (size_t)(r0 + row) * 8192 + 2048 + hk * 128 + col);
      uint4 qv = *(const uint4*)(conv + (size_t)(r0 + row) * 8192 + hk * 128 + col);
      *(uint4*)(&Kb[row * 136 + col]) = kv;
      float lam = bf2f(vb16[64 + row]);
      union { uint4 u4; unsigned short h[8]; } qq; qq.u4 = qv;
      #pragma unroll
      for (int e = 0; e < 8; e++) qq.h[e] = f2bf(bf2f(qq.h[e]) * lam);
      *(uint4*)(&Qb[row * 136 + col]) = qq.u4;
    }
    __syncthreads();
    // KS0 -> rhs -> rhsT
    {
      f32x4 acc = f32x4{0, 0, 0, 0};
      #pragma unroll
      for (int ks = 0; ks < 4; ks++) {
        int ko = ks * 32 + l4 * 8;
        bf16x8 af = *(const bf16x8*)(&Kb[(trt + l15) * 136 + ko]);
        bf16x8 bfv = *(const bf16x8*)(&S0T[(tct + l15) * 136 + ko]);
        acc = MFMA(af, bfv, acc);
      }
      #pragma unroll
      for (int r = 0; r < 4; r++) {
        int tl = trt + l4 * 4 + r;
        int t = r0 + tl;
        float beta = bf2f(betab[(size_t)t * 32 + hv]);
        float bl = bf2f(vb16[tl]);
        float vv = bf2f(conv[(size_t)t * 8192 + 4096 + hv * 128 + dv0 + tct + l15]);
        rhsT[(tct + l15) * 72 + tl] = f2bf(beta * vv - bl * acc[r]);
      }
    }
    __syncthreads();
    // O = M1@rhsT + Qhat@S0T -> write o over v
    {
      f32x4 acc = f32x4{0, 0, 0, 0};
      const unsigned short* m1b = M1g + (size_t)bhc * 4096;
      #pragma unroll
      for (int ks = 0; ks < 2; ks++) {
        int so = ks * 32 + l4 * 8;
        union { uint4 u4; bf16x8 h; } af;
        af.u4 = *(const uint4*)(m1b + (trt + l15) * 64 + so);
        bf16x8 bfv = *(const bf16x8*)(&rhsT[(tct + l15) * 72 + so]);
        acc = MFMA(af.h, bfv, acc);
      }
      #pragma unroll
      for (int ks = 0; ks < 4; ks++) {
        int ko = ks * 32 + l4 * 8;
        bf16x8 af = *(const bf16x8*)(&Qb[(trt + l15) * 136 + ko]);
        bf16x8 bfv = *(const bf16x8*)(&S0T[(tct + l15) * 136 + ko]);
        acc = MFMA(af, bfv, acc);
      }
      #pragma unroll
      for (int r = 0; r < 4; r++) {
        int t = r0 + trt + l4 * 4 + r;
        conv[(size_t)t * 8192 + 4096 + hv * 128 + dv0 + tct + l15] = f2bf(acc[r]);
      }
    }
    // S = LambdaC*S0 + M2@rhsT
    {
      float lamC = *(const float*)(vb + 256);
      f32x4 sacc[2];
      const unsigned short* m2b = M2g + (size_t)bhc * 8192;
      const int dkb = wv * 16;
      #pragma unroll
      for (int dt = 0; dt < 2; dt++) {
        int dvb = dt * 16;
        f32x4 a;
        #pragma unroll
        for (int r = 0; r < 4; r++) a[r] = lamC * Sf[(dkb + l4 * 4 + r) * 36 + dvb + l15];
        #pragma unroll
        for (int ks = 0; ks < 2; ks++) {
          int so = ks * 32 + l4 * 8;
          union { uint4 u4; bf16x8 h; } af;
          af.u4 = *(const uint4*)(m2b + (dkb + l15) * 64 + so);
          bf16x8 bfv = *(const bf16x8*)(&rhsT[(dvb + l15) * 72 + so]);
          a = MFMA(af.h, bfv, a);
        }
        sacc[dt] = a;
      }
      __syncthreads();   // all reads of S0T/Sf/rhsT complete
      #pragma unroll
      for (int dt = 0; dt < 2; dt++) {
        int dvb = dt * 16;
        #pragma unroll
        for (int r = 0; r < 4; r++) {
          int dk = dkb + l4 * 4 + r, dvl = dvb + l15;
          Sf[dk * 36 + dvl] = sacc[dt][r];
          S0T[dvl * 136 + dk] = f2bf(sacc[dt][r]);
        }
      }
    }
    __syncthreads();
  }
}

// ---------------- gated RMSNorm in-place on o (in conv_out V-section) ----------------
__global__ __launch_bounds__(256) void rmsgate_kernel(unsigned short* __restrict__ conv,
                                                      const unsigned short* __restrict__ zg,
                                                      const float* __restrict__ nw) {
  int wid = blockIdx.x * 4 + (threadIdx.x >> 6);
  int lane = threadIdx.x & 63;
  int row = wid >> 5, hv = wid & 31;
  unsigned short* op = conv + (size_t)row * 8192 + 4096 + hv * 128;
  float o0 = bf2f(op[lane]), o1 = bf2f(op[64 + lane]);
  float ss = o0 * o0 + o1 * o1;
  #pragma unroll
  for (int m = 1; m < 64; m <<= 1) ss += __shfl_xor(ss, m);
  float r = rsqrtf(ss * (1.f / 128.f) + 1e-6f);
  const unsigned short* zp = zg + (size_t)row * 4096 + hv * 128;
  float g0 = bf2f(zp[lane]), g1 = bf2f(zp[64 + lane]);
  g0 = g0 / (1.f + expf(-g0));
  g1 = g1 / (1.f + expf(-g1));
  op[lane] = f2bf(o0 * r * g0 * nw[lane]);
  op[64 + lane] = f2bf(o1 * r * g1 * nw[64 + lane]);
}

extern "C" void kernel_launch(void* const* d_in, const int* in_sizes, int n_in,
                              void* d_out, int out_size, void* d_ws, size_t ws_size,
                              hipStream_t stream) {
  (void)in_sizes; (void)n_in; (void)out_size;
  const float* x       = (const float*)d_in[0];
  const float* W_qkv   = (const float*)d_in[1];
  const float* W_z     = (const float*)d_in[2];
  const float* W_b     = (const float*)d_in[3];
  const float* W_a     = (const float*)d_in[4];
  const float* conv_w  = (const float*)d_in[5];
  const float* dt_bias = (const float*)d_in[6];
  const float* A_log   = (const float*)d_in[7];
  const float* nw      = (const float*)d_in[8];
  const float* W_out   = (const float*)d_in[9];
  float* out = (float*)d_out;

  const size_t NEED = 169115648ULL;   // <= 169,345,024 proven in round 2
  if (ws_size < NEED) return;

  char* ws = (char*)d_ws;
  // slot0 @0 (64MiB): qkv_bf -> {M1, M2} -> WoutT over M1
  unsigned short* qkv_bf = (unsigned short*)(ws + 0);
  unsigned short* M1g    = (unsigned short*)(ws + 0);
  unsigned short* M2g    = (unsigned short*)(ws + 16777216);
  unsigned short* WoutT  = (unsigned short*)(ws + 0);
  // zg @64MiB (32MiB)
  unsigned short* zg     = (unsigned short*)(ws + 67108864);
  // slot2 @96MiB (64MiB): {WzT, x_bf, WqkvT/(WbaT,ba)} -> conv_out
  unsigned short* WzT    = (unsigned short*)(ws + 100663296);
  unsigned short* x_bf   = (unsigned short*)(ws + 100663296 + 16777216);
  unsigned short* WqkvT  = (unsigned short*)(ws + 100663296 + 33554432);
  unsigned short* WbaT   = (unsigned short*)(ws + 100663296 + 33554432);
  unsigned short* ba     = (unsigned short*)(ws + 100663296 + 34078720);
  unsigned short* convb  = (unsigned short*)(ws + 100663296);
  // tail @160MiB
  unsigned short* betab  = (unsigned short*)(ws + 167772160);
  float* gbuf            = (float*)(ws + 168034304);
  unsigned char* vecs    = (unsigned char*)(ws + 168558592);

  const int M = MROWS;

  // 1) conversions + big weight transposes
  f32_to_bf16_vec<<<(M * 2048 / 4) / 256, 256, 0, stream>>>(x, x_bf, M * 2048 / 4);
  transpose_f2b<<<dim3(8192 / 32, 2048 / 32), 256, 0, stream>>>(W_qkv, WqkvT, 2048, 8192);
  transpose_f2b<<<dim3(4096 / 32, 2048 / 32), 256, 0, stream>>>(W_z, WzT, 2048, 4096);

  // 2) GEMM1 -> qkv_bf (256^2 tile, counted-vmcnt pipeline)
  gemm256<1, 256><<<512, 512, 0, stream>>>(x_bf, 2048, WqkvT, 2048, qkv_bf, 8192, M, 8192, 2048);

  // 3) small b/a weight transposes (over WqkvT, dead after GEMM1)
  transpose_f2b<<<dim3(1, 64), 256, 0, stream>>>(W_b, WbaT, 2048, 32);
  transpose_f2b<<<dim3(1, 64), 256, 0, stream>>>(W_a, WbaT + (size_t)32 * 2048, 2048, 32);

  // 4) GEMM2a -> zg ; GEMM2b -> ba
  gemm256<1, 256><<<256, 512, 0, stream>>>(x_bf, 2048, WzT, 2048, zg, 4096, M, 4096, 2048);
  gemm_bf16<1><<<dim3(1, M / 128), 256, 0, stream>>>(x_bf, 2048, WbaT, 2048, ba, 128, M, 128, 2048);

  // 5) beta/g (into tail; survives conv overwrite of slot2)
  beta_g_kernel<<<(M * 32) / 256, 256, 0, stream>>>(ba, A_log, dt_bias, betab, gbuf);

  // 6) conv -> conv_out (overwrites slot2; x_bf/WzT/WbaT/ba dead)
  conv_kernel<<<dim3(64, 64, 2), 256, 0, stream>>>(qkv_bf, conv_w, convb);

  // 7) precompute M1/M2/vecs (over qkv_bf, dead after conv)
  prep_kernel<<<dim3(32, 64), 256, 0, stream>>>(convb, gbuf, betab, M1g, M2g, vecs);

  // 8) sequential chunk recurrence; o overwrites conv_out V-section
  seq_kernel<<<dim3(4, 64), 512, 0, stream>>>(convb, M1g, M2g, vecs, betab);

  // 9) gated RMSNorm in place on o
  rmsgate_kernel<<<32768, 256, 0, stream>>>(convb, zg, nw);

  // 10) W_out transpose (over M1, dead) + final GEMM -> f32 out (256x128 tiles)
  transpose_f2b<<<dim3(2048 / 32, 4096 / 32), 256, 0, stream>>>(W_out, WoutT, 4096, 2048);
  gemm256<0, 128><<<256, 512, 0, stream>>>(convb + 4096, 8192, WoutT, 4096, out, 2048, M, 2048, 4096);
}

// Round 6
// 621.725 us; speedup vs baseline: 3.3354x; 1.1561x over previous
//
#include <hip/hip_runtime.h>

// Qwen3.5 GatedDeltaNet fwd on gfx950 — chunked delta-rule + 256^2 counted-vmcnt GEMM.
// B=2 T=2048 HID=2048 HK=16 HV=32 DK=DV=128 KW=4, chunk C=64 (32 chunks).
// R5: fix prep_kernel scratch zeroing size (896/240 uint4, was 448/120 -> NaN).

#define T_LEN 2048
#define MROWS 4096

typedef __bf16 bf16x8 __attribute__((ext_vector_type(8)));
typedef float f32x4 __attribute__((ext_vector_type(4)));

#define MFMA(a, b, c) __builtin_amdgcn_mfma_f32_16x16x32_bf16((a), (b), (c), 0, 0, 0)

__device__ __forceinline__ unsigned short f2bf(float f) {
  unsigned int u = __float_as_uint(f);
  unsigned int r = (u + 0x7fffu + ((u >> 16) & 1u)) >> 16;
  return (unsigned short)r;
}
__device__ __forceinline__ float bf2f(unsigned short u) {
  return __uint_as_float(((unsigned int)u) << 16);
}
__device__ __forceinline__ void gload_lds16(const void* g, void* l) {
  __builtin_amdgcn_global_load_lds(
      (const __attribute__((address_space(1))) unsigned int*)g,
      (__attribute__((address_space(3))) unsigned int*)l, 16, 0, 0);
}

// ---------------- elementwise f32 -> bf16 ----------------
__global__ __launch_bounds__(256) void f32_to_bf16_vec(const float* __restrict__ src,
                                                       unsigned short* __restrict__ dst,
                                                       int n4) {
  int i = blockIdx.x * 256 + threadIdx.x;
  if (i >= n4) return;
  float4 v = ((const float4*)src)[i];
  ushort4 o;
  o.x = f2bf(v.x); o.y = f2bf(v.y); o.z = f2bf(v.z); o.w = f2bf(v.w);
  ((ushort4*)dst)[i] = o;
}

// ---------------- transpose f32 [R,C] -> bf16 [C,R] ----------------
__global__ __launch_bounds__(256) void transpose_f2b(const float* __restrict__ src,
                                                     unsigned short* __restrict__ dst,
                                                     int R, int C) {
  __shared__ float tile[32][33];
  int tx = threadIdx.x & 31, ty = threadIdx.x >> 5;
  int c0 = blockIdx.x * 32, r0 = blockIdx.y * 32;
  #pragma unroll
  for (int i = ty; i < 32; i += 8)
    tile[i][tx] = src[(size_t)(r0 + i) * C + c0 + tx];
  __syncthreads();
  #pragma unroll
  for (int i = ty; i < 32; i += 8)
    dst[(size_t)(c0 + i) * R + r0 + tx] = f2bf(tile[tx][i]);
}

// ===================== 256-wide-tile GEMM, counted-vmcnt pipeline =====================
template <int OUTBF, int BN>
__global__ __launch_bounds__(512, 2) void gemm256(const unsigned short* __restrict__ A, int lda,
                                                  const unsigned short* __restrict__ Bt, int ldb,
                                                  void* __restrict__ Cv, int ldc,
                                                  int M, int N, int K) {
  constexpr int BUFSZ = 16384 + BN * 64;
  constexpr int BISS = BN / 64;
  constexpr int IS = 4 + BISS;
  constexpr int WMv = (BN == 256) ? 2 : 4;
  constexpr int MSUB = 256 / (WMv * 16);
  constexpr int MSPAN = 256 / WMv;

  __shared__ unsigned short lds[2 * BUFSZ];

  const int mtiles = M >> 8;
  const int nwg = gridDim.x;
  const int orig = blockIdx.x;
  const int q = nwg >> 3, r = nwg & 7;
  const int xcd = orig & 7, idx = orig >> 3;
  const int swz = (xcd < r ? xcd * (q + 1) : r * (q + 1) + (xcd - r) * q) + idx;
  const int m0 = (swz % mtiles) * 256;
  const int n0 = (swz / mtiles) * BN;

  const int tid = threadIdx.x, lane = tid & 63, wv = tid >> 6;
  const int wm = (BN == 256) ? (wv >> 2) : (wv >> 1);
  const int wn = (BN == 256) ? (wv & 3) : (wv & 1);
  const int l15 = lane & 15, l4 = lane >> 4;

  f32x4 acc[MSUB][4];
  #pragma unroll
  for (int i = 0; i < MSUB; i++)
    #pragma unroll
    for (int j = 0; j < 4; j++) acc[i][j] = f32x4{0.f, 0.f, 0.f, 0.f};

  const int NT = K >> 6;

  auto STAGE = [&](int kt) {
    unsigned short* base = lds + (kt & 1) * BUFSZ;
    const int k0 = kt << 6;
    #pragma unroll
    for (int is = 0; is < 4; is++) {
      int ow = is * 8192 + wv * 1024;
      int o = ow + lane * 16;
      int row = o >> 7, colB = o & 127;
      int scol = colB ^ ((row & 7) << 4);
      gload_lds16(A + (size_t)(m0 + row) * lda + k0 + (scol >> 1), base + (ow >> 1));
    }
    #pragma unroll
    for (int is = 0; is < BISS; is++) {
      int ow = is * 8192 + wv * 1024;
      int o = ow + lane * 16;
      int row = o >> 7, colB = o & 127;
      int scol = colB ^ ((row & 7) << 4);
      gload_lds16(Bt + (size_t)(n0 + row) * ldb + k0 + (scol >> 1), base + 16384 + (ow >> 1));
    }
  };

  STAGE(0);
  if (NT > 1) STAGE(1);
  if constexpr (IS == 8) asm volatile("s_waitcnt vmcnt(8)" ::: "memory");
  else                   asm volatile("s_waitcnt vmcnt(6)" ::: "memory");
  __builtin_amdgcn_sched_barrier(0);
  __builtin_amdgcn_s_barrier();
  __builtin_amdgcn_sched_barrier(0);

  for (int t = 0; t < NT; t++) {
    const unsigned short* Abuf = lds + (t & 1) * BUFSZ;
    const unsigned short* Bbuf = Abuf + 16384;
    bf16x8 bF[4][2];
    #pragma unroll
    for (int n = 0; n < 4; n++) {
      int rb = wn * 64 + n * 16 + l15;
      int sw = (rb & 7) << 4;
      #pragma unroll
      for (int ks = 0; ks < 2; ks++) {
        int colB = (ks * 32 + l4 * 8) * 2;
        bF[n][ks] = *(const bf16x8*)(Bbuf + rb * 64 + ((colB ^ sw) >> 1));
      }
    }
    __builtin_amdgcn_s_setprio(1);
    #pragma unroll
    for (int m = 0; m < MSUB; m++) {
      int ra = wm * MSPAN + m * 16 + l15;
      int sw = (ra & 7) << 4;
      int c0b = l4 * 16;
      bf16x8 a0 = *(const bf16x8*)(Abuf + ra * 64 + ((c0b ^ sw) >> 1));
      bf16x8 a1 = *(const bf16x8*)(Abuf + ra * 64 + (((64 + c0b) ^ sw) >> 1));
      #pragma unroll
      for (int n = 0; n < 4; n++) {
        acc[m][n] = MFMA(a0, bF[n][0], acc[m][n]);
        acc[m][n] = MFMA(a1, bF[n][1], acc[m][n]);
      }
    }
    __builtin_amdgcn_s_setprio(0);
    __builtin_amdgcn_sched_barrier(0);
    __builtin_amdgcn_s_barrier();
    __builtin_amdgcn_sched_barrier(0);
    if (t + 2 < NT) STAGE(t + 2);
    if (t + 1 < NT) {
      if (t + 2 < NT) {
        if constexpr (IS == 8) asm volatile("s_waitcnt vmcnt(8)" ::: "memory");
        else                   asm volatile("s_waitcnt vmcnt(6)" ::: "memory");
      } else {
        asm volatile("s_waitcnt vmcnt(0)" ::: "memory");
      }
      __builtin_amdgcn_sched_barrier(0);
      __builtin_amdgcn_s_barrier();
      __builtin_amdgcn_sched_barrier(0);
    }
  }

  #pragma unroll
  for (int m = 0; m < MSUB; m++) {
    int grow = m0 + wm * MSPAN + m * 16 + l4 * 4;
    #pragma unroll
    for (int n = 0; n < 4; n++) {
      int gcol = n0 + wn * 64 + n * 16 + l15;
      if (OUTBF) {
        unsigned short* cp = (unsigned short*)Cv + (size_t)grow * ldc + gcol;
        #pragma unroll
        for (int rr = 0; rr < 4; rr++) cp[(size_t)rr * ldc] = f2bf(acc[m][n][rr]);
      } else {
        float* cp = (float*)Cv + (size_t)grow * ldc + gcol;
        #pragma unroll
        for (int rr = 0; rr < 4; rr++) cp[(size_t)rr * ldc] = acc[m][n][rr];
      }
    }
  }
}

// ------- bf16 MFMA GEMM (128^2, small-N fallback) -------
template <int OUTBF>
__global__ __launch_bounds__(256) void gemm_bf16(const unsigned short* __restrict__ A, int lda,
                                                 const unsigned short* __restrict__ Bt, int ldb,
                                                 void* __restrict__ Cv, int ldc,
                                                 int M, int N, int K) {
  __shared__ unsigned short As[128 * 64];
  __shared__ unsigned short Bs[128 * 64];
  const int tid = threadIdx.x, lane = tid & 63, wv = tid >> 6;
  const int wr = wv >> 1, wc = wv & 1;
  const int m0 = blockIdx.y * 128, n0 = blockIdx.x * 128;
  const int lrow8 = lane >> 3;
  const int lk8 = (lane & 7) * 8;

  f32x4 acc[4][4];
  #pragma unroll
  for (int i = 0; i < 4; i++)
    #pragma unroll
    for (int j = 0; j < 4; j++) acc[i][j] = f32x4{0.f, 0.f, 0.f, 0.f};

  for (int k0 = 0; k0 < K; k0 += 64) {
    #pragma unroll
    for (int j = 0; j < 4; ++j) {
      int chunk = j * 4 + wv;
      int r = chunk * 8 + lrow8;
      gload_lds16(A + (size_t)(m0 + r) * lda + k0 + lk8, (void*)(As + chunk * 512));
      gload_lds16(Bt + (size_t)(n0 + r) * ldb + k0 + lk8, (void*)(Bs + chunk * 512));
    }
    __syncthreads();
    #pragma unroll
    for (int half = 0; half < 2; ++half) {
      int ko = half * 32 + (lane >> 4) * 8;
      bf16x8 af[4], bfr[4];
      #pragma unroll
      for (int i = 0; i < 4; i++) {
        int ra = wr * 64 + i * 16 + (lane & 15);
        af[i] = *(const bf16x8*)(As + ra * 64 + ko);
        int rb = wc * 64 + i * 16 + (lane & 15);
        bfr[i] = *(const bf16x8*)(Bs + rb * 64 + ko);
      }
      #pragma unroll
      for (int i = 0; i < 4; i++)
        #pragma unroll
        for (int j = 0; j < 4; j++)
          acc[i][j] = MFMA(af[i], bfr[j], acc[i][j]);
    }
    __syncthreads();
  }
  int cr4 = (lane >> 4) * 4;
  int cc = lane & 15;
  #pragma unroll
  for (int i = 0; i < 4; i++) {
    int row = m0 + wr * 64 + i * 16 + cr4;
    #pragma unroll
    for (int j = 0; j < 4; j++) {
      int col = n0 + wc * 64 + j * 16 + cc;
      if (OUTBF) {
        unsigned short* cp = (unsigned short*)Cv + (size_t)row * ldc + col;
        #pragma unroll
        for (int r = 0; r < 4; r++) cp[(size_t)r * ldc] = f2bf(acc[i][j][r]);
      } else {
        float* cp = (float*)Cv + (size_t)row * ldc + col;
        #pragma unroll
        for (int r = 0; r < 4; r++) cp[(size_t)r * ldc] = acc[i][j][r];
      }
    }
  }
}

// ---------------- beta / g from ba ----------------
__global__ __launch_bounds__(256) void beta_g_kernel(const unsigned short* __restrict__ ba,
                                                     const float* __restrict__ A_log,
                                                     const float* __restrict__ dt_bias,
                                                     unsigned short* __restrict__ betab,
                                                     float* __restrict__ g) {
  int i = blockIdx.x * 256 + threadIdx.x;
  int row = i >> 5, hv = i & 31;
  float rb = bf2f(ba[(size_t)row * 128 + hv]);
  float ra = bf2f(ba[(size_t)row * 128 + 32 + hv]);
  betab[i] = f2bf(1.f / (1.f + expf(-rb)));
  float xg = ra + dt_bias[hv];
  float sp = (xg > 20.f) ? xg : log1pf(expf(xg));
  g[i] = -expf(A_log[hv]) * sp;
}

// ------- conv4 + SiLU + q/k l2norm -------
__global__ __launch_bounds__(256) void conv_kernel(const unsigned short* __restrict__ qkv,
                                                   const float* __restrict__ conv_w,
                                                   unsigned short* __restrict__ out) {
  const int seg = blockIdx.x, tt = blockIdx.y, b = blockIdx.z;
  const int tid = threadIdx.x;
  const int c0 = seg * 128;
  const bool isq = seg < 16;
  int scb;
  if (isq) scb = seg * 512;
  else if (seg < 32) scb = (seg - 16) * 512 + 128;
  else scb = ((seg - 32) >> 1) * 512 + 256 + ((seg - 32) & 1) * 128;

  __shared__ unsigned short raw[35][136];
  __shared__ float cw[4][132];

  for (int i = tid; i < 512; i += 256) {
    int cl = i >> 2, tap = i & 3;
    cw[tap][cl] = conv_w[(size_t)(c0 + cl) * 4 + tap];
  }
  const int t0 = tt * 32;
  for (int i = tid; i < 560; i += 256) {
    int row = i >> 4, col = (i & 15) * 8;
    int gt = t0 - 3 + row;
    uint4 v = make_uint4(0u, 0u, 0u, 0u);
    if (gt >= 0) v = *(const uint4*)(qkv + (size_t)(b * T_LEN + gt) * 8192 + scb + col);
    *(uint4*)(&raw[row][col]) = v;
  }
  __syncthreads();
  const int s = tid >> 3, dg = tid & 7;
  union RawU { uint4 v[2]; unsigned short h[16]; };
  RawU u[4];
  #pragma unroll
  for (int i = 0; i < 4; i++) {
    const uint4* p = (const uint4*)&raw[s + i][dg * 16];
    u[i].v[0] = p[0]; u[i].v[1] = p[1];
  }
  float vals[16]; float ss = 0.f;
  #pragma unroll
  for (int j = 0; j < 16; j++) {
    float a = 0.f;
    #pragma unroll
    for (int i = 0; i < 4; i++) a = fmaf(cw[i][dg * 16 + j], bf2f(u[i].h[j]), a);
    a = a / (1.f + expf(-a));
    vals[j] = a; ss += a * a;
  }
  if (seg < 32) {
    ss += __shfl_xor(ss, 1); ss += __shfl_xor(ss, 2); ss += __shfl_xor(ss, 4);
    float sc = rsqrtf(ss + 1e-6f);
    if (isq) sc *= 0.08838834764831845f;
    #pragma unroll
    for (int j = 0; j < 16; j++) vals[j] *= sc;
  }
  union { uint4 v[2]; unsigned short h[16]; } ov;
  #pragma unroll
  for (int j = 0; j < 16; j++) ov.h[j] = f2bf(vals[j]);
  unsigned short* op = out + (size_t)(b * T_LEN + t0 + s) * 8192 + c0 + dg * 16;
  *(uint4*)(op) = ov.v[0];
  *(uint4*)(op + 8) = ov.v[1];
}

// ---------------- prep: per chunk-head precompute M1, M2, vecs ----------------
// grid (32 chunks, 64 bh); block 256 (4 waves).
// X = (I+L)^-1 via blocked 16x16: per-wave register forward-sub for diagonal
// blocks, MFMA for off-diagonal combination.
__global__ __launch_bounds__(256) void prep_kernel(const unsigned short* __restrict__ conv,
                                                   const float* __restrict__ g,
                                                   const unsigned short* __restrict__ betab,
                                                   unsigned short* __restrict__ M1g,
                                                   unsigned short* __restrict__ M2g,
                                                   unsigned char* __restrict__ vecs) {
  const int c = blockIdx.x, bh = blockIdx.y;
  const int b = bh >> 5, hv = bh & 31, hk = hv >> 1;
  const int bhc = bh * 32 + c;
  const int tid = threadIdx.x, lane = tid & 63, wv = tid >> 6;
  const int r0 = b * T_LEN + c * 64;
  const int l15 = lane & 15, l4 = lane >> 4;

  __shared__ unsigned short Kb[128 * 72];    // K staging [64][136] -> KT [128][72]
  __shared__ unsigned short QbX[64 * 136];   // Q staging; later XTb[64][72] + Xdrow[4][16][40]
  __shared__ unsigned short Lbf[64 * 72];    // strict-lower L (bf16)
  __shared__ unsigned short Pb[64 * 72];
  __shared__ unsigned short WT[3 * 16 * 40];
  __shared__ float Gs[64], SCs[64], BLs[64];

  unsigned short* Qb = QbX;
  unsigned short* XTb = QbX;             // [64][72] = 4608 ushorts
  unsigned short* Xdrow = QbX + 4608;    // [4][16][40] = 2560 ushorts

  // ---- phase 1: decay prefix + vecs (wave 0) + stage K,Q (all) ----
  if (wv == 0) {
    float gt = g[(size_t)(r0 + lane) * 32 + hv];
    #pragma unroll
    for (int d = 1; d < 64; d <<= 1) {
      float o = __shfl_up(gt, (unsigned)d, 64);
      if (lane >= d) gt += o;
    }
    float GC = __shfl(gt, 63, 64);
    float lam = expf(gt);
    float beta = bf2f(betab[(size_t)(r0 + lane) * 32 + hv]);
    Gs[lane] = gt;
    SCs[lane] = expf(GC - gt);
    BLs[lane] = beta;
    unsigned short* vb16 = (unsigned short*)(vecs + (size_t)bhc * 272);
    vb16[lane] = f2bf(beta * lam);
    vb16[64 + lane] = f2bf(lam);
    if (lane == 0) *(float*)(vecs + (size_t)bhc * 272 + 256) = expf(GC);
  }
  const unsigned short* Kg = conv + (size_t)r0 * 8192 + 2048 + hk * 128;
  const unsigned short* Qg = conv + (size_t)r0 * 8192 + hk * 128;
  for (int u = tid; u < 1024; u += 256) {
    int row = u >> 4, col = (u & 15) * 8;
    *(uint4*)(&Kb[row * 136 + col]) = *(const uint4*)(Kg + (size_t)row * 8192 + col);
    *(uint4*)(&Qb[row * 136 + col]) = *(const uint4*)(Qg + (size_t)row * 8192 + col);
  }
  __syncthreads();

  // ---- phase 2: KK^T and QK^T -> Lbf (bf16 strict-lower), Pb ----
  {
    f32x4 akk[4], aqk[4];
    #pragma unroll
    for (int st = 0; st < 4; st++) { akk[st] = f32x4{0,0,0,0}; aqk[st] = f32x4{0,0,0,0}; }
    int trow = wv * 16 + l15;
    int klo = l4 * 8;
    #pragma unroll
    for (int ks = 0; ks < 4; ks++) {
      int ko = ks * 32 + klo;
      bf16x8 ak = *(const bf16x8*)(&Kb[trow * 136 + ko]);
      bf16x8 aq = *(const bf16x8*)(&Qb[trow * 136 + ko]);
      #pragma unroll
      for (int st = 0; st < 4; st++) {
        bf16x8 bk = *(const bf16x8*)(&Kb[(st * 16 + l15) * 136 + ko]);
        akk[st] = MFMA(ak, bk, akk[st]);
        aqk[st] = MFMA(aq, bk, aqk[st]);
      }
    }
    int orow = wv * 16 + l4 * 4;
    int oc = l15;
    #pragma unroll
    for (int st = 0; st < 4; st++)
      #pragma unroll
      for (int r = 0; r < 4; r++) {
        int t = orow + r, ssv = st * 16 + oc;
        float e = expf(fminf(Gs[t] - Gs[ssv], 0.f));
        Lbf[t * 72 + ssv] = f2bf((ssv < t) ? BLs[t] * e * akk[st][r] : 0.f);
        Pb[t * 72 + ssv] = f2bf((ssv <= t) ? e * aqk[st][r] : 0.f);
      }
  }
  __syncthreads();

  // ---- phase 3: zero XTb/Xdrow/WT (Qb dead) + read K columns for KT ----
  unsigned short ktv[32];
  {
    int dk = tid >> 1, tb = (tid & 1) * 32;
    #pragma unroll
    for (int i = 0; i < 32; i++)
      ktv[i] = f2bf(bf2f(Kb[(tb + i) * 136 + dk]) * SCs[tb + i]);
    for (int u = tid; u < 896; u += 256) {      // XTb+Xdrow: 7168 ushorts = 896 uint4
      *(uint4*)(&QbX[u * 8]) = make_uint4(0u, 0u, 0u, 0u);
    }
    for (int u = tid; u < 240; u += 256) {      // WT: 1920 ushorts = 240 uint4
      *(uint4*)(&WT[u * 8]) = make_uint4(0u, 0u, 0u, 0u);
    }
  }
  __syncthreads();

  // ---- phase 4: KT write (in-place over staging) + diagonal block inversion ----
  {
    int dk = tid >> 1, tb = (tid & 1) * 32;
    #pragma unroll
    for (int i = 0; i < 32; i++) Kb[dk * 72 + tb + i] = ktv[i];
  }
  {
    // wave wv inverts diag block wv: lanes replicate over c = lane&15
    const int w16 = wv * 16;
    const int cc = l15;
    float xr[16];
    #pragma unroll
    for (int t = 0; t < 16; t++) {
      float acc = (cc == t) ? 1.f : 0.f;
      union { uint4 v[2]; unsigned short h[16]; } rw;
      const uint4* p = (const uint4*)(&Lbf[(w16 + t) * 72 + w16]);
      rw.v[0] = p[0]; rw.v[1] = p[1];
      #pragma unroll
      for (int s = 0; s < 16; s++) {
        if (s < t) acc = fmaf(-bf2f(rw.h[s]), xr[s], acc);
      }
      xr[t] = acc;
    }
    if (lane < 16) {
      #pragma unroll
      for (int t = 0; t < 16; t++) {
        unsigned short v = f2bf(xr[t]);
        XTb[(w16 + cc) * 72 + w16 + t] = v;       // X[s][col] transposed store
        Xdrow[wv * 640 + t * 40 + cc] = v;        // row-major Xd
      }
    }
  }
  __syncthreads();

  // ---- phase 5: off-diagonal blocks, wave j handles column block j ----
  if (wv < 3) {
    const int j = wv;
    for (int i = j + 1; i < 4; i++) {
      // W = sum_k A[i][k] X[k][j] over full K (unwritten X blocks are zero)
      f32x4 w_ = f32x4{0.f, 0.f, 0.f, 0.f};
      #pragma unroll
      for (int ks = 0; ks < 2; ks++) {
        int so = ks * 32 + l4 * 8;
        bf16x8 af = *(const bf16x8*)(&Lbf[(i * 16 + l15) * 72 + so]);
        bf16x8 bfv = *(const bf16x8*)(&XTb[(j * 16 + l15) * 72 + so]);
        w_ = MFMA(af, bfv, w_);
      }
      // WT[j][col][row] = -W[row][col]
      #pragma unroll
      for (int r = 0; r < 4; r++)
        WT[j * 640 + l15 * 40 + l4 * 4 + r] = f2bf(-w_[r]);
      // X[i][j] = Xd[i] * (-W)
      f32x4 xij = f32x4{0.f, 0.f, 0.f, 0.f};
      {
        bf16x8 af = *(const bf16x8*)(&Xdrow[i * 640 + l15 * 40 + l4 * 8]);
        bf16x8 bfv = *(const bf16x8*)(&WT[j * 640 + l15 * 40 + l4 * 8]);
        xij = MFMA(af, bfv, xij);
      }
      #pragma unroll
      for (int r = 0; r < 4; r++)
        XTb[(j * 16 + l15) * 72 + i * 16 + l4 * 4 + r] = f2bf(xij[r]);
    }
  }
  __syncthreads();

  // ---- phase 6: M1 = Pb@X (16 tiles), M2 = KT@X (32 tiles); 12 tiles/wave ----
  for (int tt = wv * 12; tt < wv * 12 + 12; tt++) {
    f32x4 acc = f32x4{0, 0, 0, 0};
    const unsigned short* Abase;
    int mrow, jc;
    if (tt < 16) { mrow = (tt >> 2) * 16; jc = (tt & 3) * 16; Abase = Pb + mrow * 72; }
    else { int i2 = tt - 16; mrow = (i2 >> 2) * 16; jc = (i2 & 3) * 16; Abase = Kb + mrow * 72; }
    #pragma unroll
    for (int ks = 0; ks < 2; ks++) {
      int so = ks * 32 + l4 * 8;
      bf16x8 af = *(const bf16x8*)(Abase + l15 * 72 + so);
      bf16x8 bfv = *(const bf16x8*)(&XTb[(jc + l15) * 72 + so]);
      acc = MFMA(af, bfv, acc);
    }
    int ro = mrow + l4 * 4, co = jc + l15;
    if (tt < 16) {
      #pragma unroll
      for (int r = 0; r < 4; r++)
        M1g[(size_t)bhc * 4096 + (ro + r) * 64 + co] = f2bf(acc[r]);
    } else {
      #pragma unroll
      for (int r = 0; r < 4; r++)
        M2g[(size_t)bhc * 8192 + (ro + r) * 64 + co] = f2bf(acc[r]);
    }
  }
}

// ---------------- sequential chunk recurrence ----------------
__global__ __launch_bounds__(512) void seq_kernel(unsigned short* __restrict__ conv,
                                                  const unsigned short* __restrict__ M1g,
                                                  const unsigned short* __restrict__ M2g,
                                                  const unsigned char* __restrict__ vecs,
                                                  const unsigned short* __restrict__ betab) {
  const int dvs = blockIdx.x, bh = blockIdx.y;
  const int b = bh >> 5, hv = bh & 31, hk = hv >> 1;
  const int dv0 = dvs * 32;
  const int tid = threadIdx.x, lane = tid & 63, wv = tid >> 6;

  __shared__ unsigned short Kb[64 * 136], Qb[64 * 136];
  __shared__ float Sf[128 * 36];
  __shared__ unsigned short S0T[32 * 136];
  __shared__ unsigned short rhsT[32 * 72];

  for (int i = tid; i < 128 * 36; i += 512) Sf[i] = 0.f;
  for (int i = tid; i < 32 * 136; i += 512) S0T[i] = 0;
  __syncthreads();

  const int l15 = lane & 15, l4 = lane >> 4;
  const int trt = (wv >> 1) * 16;
  const int tct = (wv & 1) * 16;

  for (int c = 0; c < 32; c++) {
    const int r0 = b * T_LEN + c * 64;
    const int bhc = bh * 32 + c;
    const unsigned char* vb = vecs + (size_t)bhc * 272;
    const unsigned short* vb16 = (const unsigned short*)vb;
    #pragma unroll
    for (int j = 0; j < 2; j++) {
      int u = tid * 2 + j;
      int row = u >> 4, col = (u & 15) * 8;
      uint4 kv = *(const uint4*)(conv + (size_t)(r0 + row) * 8192 + 2048 + hk * 128 + col);
      uint4 qv = *(const uint4*)(conv + (size_t)(r0 + row) * 8192 + hk * 128 + col);
      *(uint4*)(&Kb[row * 136 + col]) = kv;
      float lam = bf2f(vb16[64 + row]);
      union { uint4 u4; unsigned short h[8]; } qq; qq.u4 = qv;
      #pragma unroll
      for (int e = 0; e < 8; e++) qq.h[e] = f2bf(bf2f(qq.h[e]) * lam);
      *(uint4*)(&Qb[row * 136 + col]) = qq.u4;
    }
    __syncthreads();
    {
      f32x4 acc = f32x4{0, 0, 0, 0};
      #pragma unroll
      for (int ks = 0; ks < 4; ks++) {
        int ko = ks * 32 + l4 * 8;
        bf16x8 af = *(const bf16x8*)(&Kb[(trt + l15) * 136 + ko]);
        bf16x8 bfv = *(const bf16x8*)(&S0T[(tct + l15) * 136 + ko]);
        acc = MFMA(af, bfv, acc);
      }
      #pragma unroll
      for (int r = 0; r < 4; r++) {
        int tl = trt + l4 * 4 + r;
        int t = r0 + tl;
        float beta = bf2f(betab[(size_t)t * 32 + hv]);
        float bl = bf2f(vb16[tl]);
        float vv = bf2f(conv[(size_t)t * 8192 + 4096 + hv * 128 + dv0 + tct + l15]);
        rhsT[(tct + l15) * 72 + tl] = f2bf(beta * vv - bl * acc[r]);
      }
    }
    __syncthreads();
    {
      f32x4 acc = f32x4{0, 0, 0, 0};
      const unsigned short* m1b = M1g + (size_t)bhc * 4096;
      #pragma unroll
      for (int ks = 0; ks < 2; ks++) {
        int so = ks * 32 + l4 * 8;
        union { uint4 u4; bf16x8 h; } af;
        af.u4 = *(const uint4*)(m1b + (trt + l15) * 64 + so);
        bf16x8 bfv = *(const bf16x8*)(&rhsT[(tct + l15) * 72 + so]);
        acc = MFMA(af.h, bfv, acc);
      }
      #pragma unroll
      for (int ks = 0; ks < 4; ks++) {
        int ko = ks * 32 + l4 * 8;
        bf16x8 af = *(const bf16x8*)(&Qb[(trt + l15) * 136 + ko]);
        bf16x8 bfv = *(const bf16x8*)(&S0T[(tct + l15) * 136 + ko]);
        acc = MFMA(af, bfv, acc);
      }
      #pragma unroll
      for (int r = 0; r < 4; r++) {
        int t = r0 + trt + l4 * 4 + r;
        conv[(size_t)t * 8192 + 4096 + hv * 128 + dv0 + tct + l15] = f2bf(acc[r]);
      }
    }
    {
      float lamC = *(const float*)(vb + 256);
      f32x4 sacc[2];
      const unsigned short* m2b = M2g + (size_t)bhc * 8192;
      const int dkb = wv * 16;
      #pragma unroll
      for (int dt = 0; dt < 2; dt++) {
        int dvb = dt * 16;
        f32x4 a;
        #pragma unroll
        for (int r = 0; r < 4; r++) a[r] = lamC * Sf[(dkb + l4 * 4 + r) * 36 + dvb + l15];
        #pragma unroll
        for (int ks = 0; ks < 2; ks++) {
          int so = ks * 32 + l4 * 8;
          union { uint4 u4; bf16x8 h; } af;
          af.u4 = *(const uint4*)(m2b + (dkb + l15) * 64 + so);
          bf16x8 bfv = *(const bf16x8*)(&rhsT[(dvb + l15) * 72 + so]);
          a = MFMA(af.h, bfv, a);
        }
        sacc[dt] = a;
      }
      __syncthreads();
      #pragma unroll
      for (int dt = 0; dt < 2; dt++) {
        int dvb = dt * 16;
        #pragma unroll
        for (int r = 0; r < 4; r++) {
          int dk = dkb + l4 * 4 + r, dvl = dvb + l15;
          Sf[dk * 36 + dvl] = sacc[dt][r];
          S0T[dvl * 136 + dk] = f2bf(sacc[dt][r]);
        }
      }
    }
    __syncthreads();
  }
}

// ---------------- gated RMSNorm in-place on o ----------------
__global__ __launch_bounds__(256) void rmsgate_kernel(unsigned short* __restrict__ conv,
                                                      const unsigned short* __restrict__ zg,
                                                      const float* __restrict__ nw) {
  int wid = blockIdx.x * 4 + (threadIdx.x >> 6);
  int lane = threadIdx.x & 63;
  int row = wid >> 5, hv = wid & 31;
  unsigned short* op = conv + (size_t)row * 8192 + 4096 + hv * 128;
  float o0 = bf2f(op[lane]), o1 = bf2f(op[64 + lane]);
  float ss = o0 * o0 + o1 * o1;
  #pragma unroll
  for (int m = 1; m < 64; m <<= 1) ss += __shfl_xor(ss, m);
  float r = rsqrtf(ss * (1.f / 128.f) + 1e-6f);
  const unsigned short* zp = zg + (size_t)row * 4096 + hv * 128;
  float g0 = bf2f(zp[lane]), g1 = bf2f(zp[64 + lane]);
  g0 = g0 / (1.f + expf(-g0));
  g1 = g1 / (1.f + expf(-g1));
  op[lane] = f2bf(o0 * r * g0 * nw[lane]);
  op[64 + lane] = f2bf(o1 * r * g1 * nw[64 + lane]);
}

extern "C" void kernel_launch(void* const* d_in, const int* in_sizes, int n_in,
                              void* d_out, int out_size, void* d_ws, size_t ws_size,
                              hipStream_t stream) {
  (void)in_sizes; (void)n_in; (void)out_size;
  const float* x       = (const float*)d_in[0];
  const float* W_qkv   = (const float*)d_in[1];
  const float* W_z     = (const float*)d_in[2];
  const float* W_b     = (const float*)d_in[3];
  const float* W_a     = (const float*)d_in[4];
  const float* conv_w  = (const float*)d_in[5];
  const float* dt_bias = (const float*)d_in[6];
  const float* A_log   = (const float*)d_in[7];
  const float* nw      = (const float*)d_in[8];
  const float* W_out   = (const float*)d_in[9];
  float* out = (float*)d_out;

  const size_t NEED = 169115648ULL;
  if (ws_size < NEED) return;

  char* ws = (char*)d_ws;
  unsigned short* qkv_bf = (unsigned short*)(ws + 0);
  unsigned short* M1g    = (unsigned short*)(ws + 0);
  unsigned short* M2g    = (unsigned short*)(ws + 16777216);
  unsigned short* WoutT  = (unsigned short*)(ws + 0);
  unsigned short* zg     = (unsigned short*)(ws + 67108864);
  unsigned short* WzT    = (unsigned short*)(ws + 100663296);
  unsigned short* x_bf   = (unsigned short*)(ws + 100663296 + 16777216);
  unsigned short* WqkvT  = (unsigned short*)(ws + 100663296 + 33554432);
  unsigned short* WbaT   = (unsigned short*)(ws + 100663296 + 33554432);
  unsigned short* ba     = (unsigned short*)(ws + 100663296 + 34078720);
  unsigned short* convb  = (unsigned short*)(ws + 100663296);
  unsigned short* betab  = (unsigned short*)(ws + 167772160);
  float* gbuf            = (float*)(ws + 168034304);
  unsigned char* vecs    = (unsigned char*)(ws + 168558592);

  const int M = MROWS;

  f32_to_bf16_vec<<<(M * 2048 / 4) / 256, 256, 0, stream>>>(x, x_bf, M * 2048 / 4);
  transpose_f2b<<<dim3(8192 / 32, 2048 / 32), 256, 0, stream>>>(W_qkv, WqkvT, 2048, 8192);
  transpose_f2b<<<dim3(4096 / 32, 2048 / 32), 256, 0, stream>>>(W_z, WzT, 2048, 4096);

  gemm256<1, 256><<<512, 512, 0, stream>>>(x_bf, 2048, WqkvT, 2048, qkv_bf, 8192, M, 8192, 2048);

  transpose_f2b<<<dim3(1, 64), 256, 0, stream>>>(W_b, WbaT, 2048, 32);
  transpose_f2b<<<dim3(1, 64), 256, 0, stream>>>(W_a, WbaT + (size_t)32 * 2048, 2048, 32);

  gemm256<1, 256><<<256, 512, 0, stream>>>(x_bf, 2048, WzT, 2048, zg, 4096, M, 4096, 2048);
  gemm_bf16<1><<<dim3(1, M / 128), 256, 0, stream>>>(x_bf, 2048, WbaT, 2048, ba, 128, M, 128, 2048);

  beta_g_kernel<<<(M * 32) / 256, 256, 0, stream>>>(ba, A_log, dt_bias, betab, gbuf);

  conv_kernel<<<dim3(64, 64, 2), 256, 0, stream>>>(qkv_bf, conv_w, convb);

  prep_kernel<<<dim3(32, 64), 256, 0, stream>>>(convb, gbuf, betab, M1g, M2g, vecs);

  seq_kernel<<<dim3(4, 64), 512, 0, stream>>>(convb, M1g, M2g, vecs, betab);

  rmsgate_kernel<<<32768, 256, 0, stream>>>(convb, zg, nw);

  transpose_f2b<<<dim3(2048 / 32, 4096 / 32), 256, 0, stream>>>(W_out, WoutT, 4096, 2048);
  gemm256<0, 128><<<256, 512, 0, stream>>>(convb + 4096, 8192, WoutT, 4096, out, 2048, M, 2048, 4096);
}